// Round 1
// baseline (559.224 us; speedup 1.0000x reference)
//
#include <hip/hip_runtime.h>
#include <math.h>

#define DI __device__ __forceinline__

static constexpr int Cc = 256;
static constexpr int Nn = 4096;   // 64*64 spatial

DI float hswish(float v) { return v * fminf(fmaxf(v + 3.f, 0.f), 6.f) * (1.f / 6.f); }

// ---------------------------------------------------------------------------
// K1: qkv gemm. Out[g][c][n] = sum_k Wg[c*256+k] * In[n*256+k]
// g in [0,24): 0..7 = Q (seg @ q_w), 8..15 = K (x @ kv_w[0:256]), 16..23 = V.
// Tile: 128c x 128n, K-chunk 16, 8x8 acc per thread (n split {tn, 64+tn}).
// ---------------------------------------------------------------------------
__global__ __launch_bounds__(256) void k_qkv(
    const float* __restrict__ x, const float* __restrict__ seg,
    const float* __restrict__ kv_w, const float* __restrict__ q_w,
    float* __restrict__ qkv)
{
  __shared__ float Il[16][128];
  __shared__ float Wl[16][128];
  const int t  = threadIdx.x;
  const int n0 = blockIdx.x * 128;
  const int c0 = blockIdx.y * 128;
  const int g  = blockIdx.z;
  const int grp = g >> 3, b = g & 7;
  const float* __restrict__ In = (grp == 0 ? seg : x) + (size_t)b * Nn * Cc;
  const float* __restrict__ Wg = (grp == 0) ? q_w : (kv_w + (grp == 2 ? Cc * Cc : 0));

  const int tn = (t & 15) * 4;
  const int tc = (t >> 4) * 8;

  float acc[8][8];
#pragma unroll
  for (int i = 0; i < 8; ++i)
#pragma unroll
    for (int j = 0; j < 8; ++j) acc[i][j] = 0.f;

  for (int kc = 0; kc < Cc; kc += 16) {
#pragma unroll
    for (int i = 0; i < 2; ++i) {
      int e = t + i * 256;
      int row = e & 127, k0 = (e >> 7) << 2;
      float4 v = *(const float4*)(In + (size_t)(n0 + row) * Cc + kc + k0);
      Il[k0 + 0][row] = v.x; Il[k0 + 1][row] = v.y;
      Il[k0 + 2][row] = v.z; Il[k0 + 3][row] = v.w;
      float4 w = *(const float4*)(Wg + (size_t)(c0 + row) * Cc + kc + k0);
      Wl[k0 + 0][row] = w.x; Wl[k0 + 1][row] = w.y;
      Wl[k0 + 2][row] = w.z; Wl[k0 + 3][row] = w.w;
    }
    __syncthreads();
#pragma unroll
    for (int k = 0; k < 16; ++k) {
      const float4 i0 = *(const float4*)&Il[k][tn];
      const float4 i1 = *(const float4*)&Il[k][64 + tn];
      const float4 w0 = *(const float4*)&Wl[k][tc];
      const float4 w1 = *(const float4*)&Wl[k][tc + 4];
      const float iv[8] = {i0.x, i0.y, i0.z, i0.w, i1.x, i1.y, i1.z, i1.w};
      const float wv[8] = {w0.x, w0.y, w0.z, w0.w, w1.x, w1.y, w1.z, w1.w};
#pragma unroll
      for (int i = 0; i < 8; ++i)
#pragma unroll
        for (int j = 0; j < 8; ++j) acc[i][j] += wv[i] * iv[j];
    }
    __syncthreads();
  }
  float* __restrict__ outp = qkv + (size_t)(g * Cc + c0 + tc) * Nn + n0;
#pragma unroll
  for (int i = 0; i < 8; ++i) {
    float4 o0 = make_float4(acc[i][0], acc[i][1], acc[i][2], acc[i][3]);
    float4 o1 = make_float4(acc[i][4], acc[i][5], acc[i][6], acc[i][7]);
    *(float4*)(outp + (size_t)i * Nn + tn) = o0;
    *(float4*)(outp + (size_t)i * Nn + 64 + tn) = o1;
  }
}

// ---------------------------------------------------------------------------
// Depthwise conv on one 64x64 plane staged in zero-padded LDS (pad 3).
// Each thread: one column x, 16 rows; register-rolled rows: (16+2P)*KS reads,
// 16*KS*KS FMA. jax conv_general_dilated = cross-correlation (no flip).
// ---------------------------------------------------------------------------
template <int KS>
DI void dw_plane(const float* __restrict__ sp, const float* __restrict__ wl,
                 float* __restrict__ dst, float bias, int t)
{
  constexpr int P = KS / 2;
  float wr[KS * KS];
#pragma unroll
  for (int i = 0; i < KS * KS; ++i) wr[i] = wl[i];
  const int x = t & 63;
  const int yb = (t >> 6) << 4;
  float acc[16];
#pragma unroll
  for (int i = 0; i < 16; ++i) acc[i] = bias;
#pragma unroll
  for (int r = 0; r < 16 + 2 * P; ++r) {
    float v[KS];
    const float* rp = sp + (yb + r + (3 - P)) * 70 + x + (3 - P);
#pragma unroll
    for (int dx = 0; dx < KS; ++dx) v[dx] = rp[dx];
#pragma unroll
    for (int dy = 0; dy < KS; ++dy) {
      const int yl = r - dy;
      if (yl >= 0 && yl < 16) {
        float s = acc[yl];
#pragma unroll
        for (int dx = 0; dx < KS; ++dx) s += wr[dy * KS + dx] * v[dx];
        acc[yl] = s;
      }
    }
  }
#pragma unroll
  for (int yl = 0; yl < 16; ++yl) dst[(yb + yl) * 64 + x] = acc[yl];
}

// K2: all depthwise convs feeding the pw stages.
// planes 0..4607:   g = p/192, c = p%192, branch r=c/64 -> KS=3/5/7 on qkv[g][c]
// planes 4608..6143: agg0 interleave: b=q/192, j=q%192 -> 3x3 on
//                    qkv[(j/64)*8+b][192+j%64] with agg0_dw[j].
__global__ __launch_bounds__(256) void k_dw(
    const float* __restrict__ qkv,
    const float* __restrict__ a1w, const float* __restrict__ a2w,
    const float* __restrict__ a3w, const float* __restrict__ a0w,
    float* __restrict__ dwout, float* __restrict__ dwout0)
{
  __shared__ float sp[70 * 70];
  __shared__ float wl[49];
  const int t = threadIdx.x;
  const int p = blockIdx.x;
  const float* src; float* dst; const float* wsp; int ks;
  if (p < 4608) {
    int g = p / 192, c = p % 192, r = c >> 6;
    ks = 3 + 2 * r;
    wsp = (r == 0 ? a1w : (r == 1 ? a2w : a3w)) + (c & 63) * ks * ks;
    src = qkv + (size_t)(g * 256 + c) * Nn;
    dst = dwout + (size_t)p * Nn;
  } else {
    int q = p - 4608;
    int b = q / 192, j = q % 192;
    ks = 3;
    wsp = a0w + j * 9;
    src = qkv + (size_t)(((j >> 6) * 8 + b) * 256 + 192 + (j & 63)) * Nn;
    dst = dwout0 + (size_t)q * Nn;
  }
  for (int i = t; i < 4900; i += 256) sp[i] = 0.f;
  if (t < 49) wl[t] = (t < ks * ks) ? wsp[t] : 0.f;
  __syncthreads();
#pragma unroll
  for (int i = 0; i < 16; ++i) {
    int e = t + i * 256;
    sp[((e >> 6) + 3) * 70 + (e & 63) + 3] = src[e];
  }
  __syncthreads();
  if (ks == 3)      dw_plane<3>(sp, wl, dst, 0.f, t);
  else if (ks == 5) dw_plane<5>(sp, wl, dst, 0.f, t);
  else              dw_plane<7>(sp, wl, dst, 0.f, t);
}

// K7: crpe depthwise convs on the V images (xc images 16..23) with bias.
__global__ __launch_bounds__(256) void k_crpe(
    const float* __restrict__ xc,
    const float* __restrict__ w3, const float* __restrict__ b3,
    const float* __restrict__ w5, const float* __restrict__ b5,
    const float* __restrict__ w7, const float* __restrict__ b7,
    float* __restrict__ conv_v)
{
  __shared__ float sp[70 * 70];
  __shared__ float wl[49];
  const int t = threadIdx.x;
  const int p = blockIdx.x;               // b*192 + ch
  const int b = p / 192, ch = p % 192;
  const float* wsp; float bias; int ks;
  if (ch < 48)       { ks = 3; wsp = w3 + ch * 9;          bias = b3[ch]; }
  else if (ch < 120) { ks = 5; wsp = w5 + (ch - 48) * 25;  bias = b5[ch - 48]; }
  else               { ks = 7; wsp = w7 + (ch - 120) * 49; bias = b7[ch - 120]; }
  const float* src = xc + (size_t)((16 + b) * 192 + ch) * Nn;
  float* dst = conv_v + (size_t)p * Nn;
  for (int i = t; i < 4900; i += 256) sp[i] = 0.f;
  if (t < 49) wl[t] = (t < ks * ks) ? wsp[t] : 0.f;
  __syncthreads();
#pragma unroll
  for (int i = 0; i < 16; ++i) {
    int e = t + i * 256;
    sp[((e >> 6) + 3) * 70 + (e & 63) + 3] = src[e];
  }
  __syncthreads();
  if (ks == 3)      dw_plane<3>(sp, wl, dst, bias, t);
  else if (ks == 5) dw_plane<5>(sp, wl, dst, bias, t);
  else              dw_plane<7>(sp, wl, dst, bias, t);
}

// ---------------------------------------------------------------------------
// K3: pointwise 64->64 + batchnorm + hardswish -> xc[g][r*64+co][n]
// Tile 64co x 128n, full K=64 staged once.
// ---------------------------------------------------------------------------
__global__ __launch_bounds__(256) void k_pw_bn(
    const float* __restrict__ dwout,
    const float* __restrict__ w1, const float* __restrict__ w2, const float* __restrict__ w3,
    const float* __restrict__ g1, const float* __restrict__ be1, const float* __restrict__ m1, const float* __restrict__ v1,
    const float* __restrict__ g2, const float* __restrict__ be2, const float* __restrict__ m2, const float* __restrict__ v2,
    const float* __restrict__ g3, const float* __restrict__ be3, const float* __restrict__ m3, const float* __restrict__ v3,
    float* __restrict__ xc)
{
  __shared__ float Tl[64][128];
  __shared__ float Wt[64][64];
  const int t = threadIdx.x;
  const int n0 = blockIdx.x * 128;
  const int r = blockIdx.y;
  const int g = blockIdx.z;
  const float* Wp = (r == 0 ? w1 : (r == 1 ? w2 : w3));
  const float* bg = (r == 0 ? g1 : (r == 1 ? g2 : g3));
  const float* bb = (r == 0 ? be1 : (r == 1 ? be2 : be3));
  const float* bm = (r == 0 ? m1 : (r == 1 ? m2 : m3));
  const float* bv = (r == 0 ? v1 : (r == 1 ? v2 : v3));
  const size_t ibase = (size_t)(g * 192 + r * 64) * Nn + n0;
#pragma unroll
  for (int i = 0; i < 8; ++i) {
    int e = t + i * 256;                  // < 2048 float4s
    int ci = e >> 5, nf = (e & 31) * 4;
    *(float4*)&Tl[ci][nf] = *(const float4*)(dwout + ibase + (size_t)ci * Nn + nf);
  }
#pragma unroll
  for (int i = 0; i < 16; ++i) {
    int e = t + i * 256;                  // < 4096
    int co = e & 63, ci = e >> 6;
    Wt[ci][co] = Wp[co * 64 + ci];
  }
  __syncthreads();
  const int tn = (t & 15) * 4;
  const int tc = (t >> 4) * 4;
  float acc[4][8];
#pragma unroll
  for (int i = 0; i < 4; ++i)
#pragma unroll
    for (int j = 0; j < 8; ++j) acc[i][j] = 0.f;
#pragma unroll 8
  for (int ci = 0; ci < 64; ++ci) {
    const float4 i0 = *(const float4*)&Tl[ci][tn];
    const float4 i1 = *(const float4*)&Tl[ci][64 + tn];
    const float4 wv = *(const float4*)&Wt[ci][tc];
    const float iv[8] = {i0.x, i0.y, i0.z, i0.w, i1.x, i1.y, i1.z, i1.w};
    const float wa[4] = {wv.x, wv.y, wv.z, wv.w};
#pragma unroll
    for (int i = 0; i < 4; ++i)
#pragma unroll
      for (int j = 0; j < 8; ++j) acc[i][j] += wa[i] * iv[j];
  }
  const size_t obase = (size_t)(g * 192 + r * 64 + tc) * Nn + n0;
#pragma unroll
  for (int i = 0; i < 4; ++i) {
    int co = tc + i;
    float sc = bg[co] * rsqrtf(bv[co] + 1e-5f);
    float sh = bb[co] - bm[co] * sc;
    float4 o0, o1;
    o0.x = hswish(acc[i][0] * sc + sh); o0.y = hswish(acc[i][1] * sc + sh);
    o0.z = hswish(acc[i][2] * sc + sh); o0.w = hswish(acc[i][3] * sc + sh);
    o1.x = hswish(acc[i][4] * sc + sh); o1.y = hswish(acc[i][5] * sc + sh);
    o1.z = hswish(acc[i][6] * sc + sh); o1.w = hswish(acc[i][7] * sc + sh);
    *(float4*)(xc + obase + (size_t)i * Nn + tn) = o0;
    *(float4*)(xc + obase + (size_t)i * Nn + 64 + tn) = o1;
  }
}

// ---------------------------------------------------------------------------
// K4: agg0 pointwise 192->64 + layernorm(over 64 ch) + hardswish
// -> x_agg0[b][n][co] (row-major co).
// ---------------------------------------------------------------------------
__global__ __launch_bounds__(256) void k_pw_ln(
    const float* __restrict__ dwout0, const float* __restrict__ pw,
    const float* __restrict__ lng, const float* __restrict__ lnb,
    float* __restrict__ x_agg0)
{
  __shared__ float Tl[64][128];           // 8192 floats; reused for reductions
  __shared__ float Wt[64][64];
  const int t = threadIdx.x;
  const int n0 = blockIdx.x * 128;
  const int b = blockIdx.y;
  const int tn = (t & 15) * 4;
  const int tc = (t >> 4) * 4;
  float acc[4][8];
#pragma unroll
  for (int i = 0; i < 4; ++i)
#pragma unroll
    for (int j = 0; j < 8; ++j) acc[i][j] = 0.f;

  for (int kc = 0; kc < 192; kc += 64) {
#pragma unroll
    for (int i = 0; i < 8; ++i) {
      int e = t + i * 256;
      int ci = e >> 5, nf = (e & 31) * 4;
      *(float4*)&Tl[ci][nf] =
          *(const float4*)(dwout0 + (size_t)(b * 192 + kc + ci) * Nn + n0 + nf);
    }
#pragma unroll
    for (int i = 0; i < 16; ++i) {
      int e = t + i * 256;
      int co = e & 63, ci = e >> 6;
      Wt[ci][co] = pw[co * 192 + kc + ci];
    }
    __syncthreads();
#pragma unroll 8
    for (int ci = 0; ci < 64; ++ci) {
      const float4 i0 = *(const float4*)&Tl[ci][tn];
      const float4 i1 = *(const float4*)&Tl[ci][64 + tn];
      const float4 wv = *(const float4*)&Wt[ci][tc];
      const float iv[8] = {i0.x, i0.y, i0.z, i0.w, i1.x, i1.y, i1.z, i1.w};
      const float wa[4] = {wv.x, wv.y, wv.z, wv.w};
#pragma unroll
      for (int i = 0; i < 4; ++i)
#pragma unroll
        for (int j = 0; j < 8; ++j) acc[i][j] += wa[i] * iv[j];
    }
    __syncthreads();
  }
  float* redS = &Tl[0][0];
  float* redQ = &Tl[0][0] + 2048;
  float* muA = &Tl[0][0] + 4096;
  float* isA = &Tl[0][0] + 4224;
#pragma unroll
  for (int j = 0; j < 8; ++j) {
    int nl = (j < 4) ? (tn + j) : (64 + tn + j - 4);
    float s = acc[0][j] + acc[1][j] + acc[2][j] + acc[3][j];
    float q = acc[0][j] * acc[0][j] + acc[1][j] * acc[1][j] +
              acc[2][j] * acc[2][j] + acc[3][j] * acc[3][j];
    redS[(t >> 4) * 128 + nl] = s;
    redQ[(t >> 4) * 128 + nl] = q;
  }
  __syncthreads();
  if (t < 128) {
    float s = 0.f, q = 0.f;
#pragma unroll
    for (int rr = 0; rr < 16; ++rr) { s += redS[rr * 128 + t]; q += redQ[rr * 128 + t]; }
    float mu = s * (1.f / 64.f);
    float var = q * (1.f / 64.f) - mu * mu;
    muA[t] = mu;
    isA[t] = rsqrtf(var + 1e-5f);
  }
  __syncthreads();
  float lg[4], lb[4];
#pragma unroll
  for (int i = 0; i < 4; ++i) { lg[i] = lng[tc + i]; lb[i] = lnb[tc + i]; }
#pragma unroll
  for (int j = 0; j < 8; ++j) {
    int nl = (j < 4) ? (tn + j) : (64 + tn + j - 4);
    float mu = muA[nl], is = isA[nl];
    float4 o;
    o.x = hswish((acc[0][j] - mu) * is * lg[0] + lb[0]);
    o.y = hswish((acc[1][j] - mu) * is * lg[1] + lb[1]);
    o.z = hswish((acc[2][j] - mu) * is * lg[2] + lb[2]);
    o.w = hswish((acc[3][j] - mu) * is * lg[3] + lb[3]);
    *(float4*)(x_agg0 + (size_t)((b << 12) + n0 + nl) * 64 + tc) = o;
  }
}

// ---------------------------------------------------------------------------
// K5: per-(b,h,c) softmax stats over N: ls = max + log(sum(exp(x-max)))
// ---------------------------------------------------------------------------
__global__ __launch_bounds__(256) void k_sm(const float* __restrict__ xc,
                                            float* __restrict__ ls)
{
  __shared__ float rA[4], rB[4];
  const int rho = blockIdx.x;             // b*192 + h*24 + c
  const int b = rho / 192, rem = rho % 192;
  const float* row = xc + (size_t)((8 + b) * 192 + rem) * Nn;
  const int t = threadIdx.x;
  float v[16];
#pragma unroll
  for (int i = 0; i < 16; ++i) v[i] = row[t + i * 256];
  float m = v[0];
#pragma unroll
  for (int i = 1; i < 16; ++i) m = fmaxf(m, v[i]);
#pragma unroll
  for (int off = 32; off > 0; off >>= 1) m = fmaxf(m, __shfl_xor(m, off, 64));
  if ((t & 63) == 0) rA[t >> 6] = m;
  __syncthreads();
  m = fmaxf(fmaxf(rA[0], rA[1]), fmaxf(rA[2], rA[3]));
  float s = 0.f;
#pragma unroll
  for (int i = 0; i < 16; ++i) s += __expf(v[i] - m);
#pragma unroll
  for (int off = 32; off > 0; off >>= 1) s += __shfl_xor(s, off, 64);
  if ((t & 63) == 0) rB[t >> 6] = s;
  __syncthreads();
  if (t == 0) ls[rho] = m + __logf(rB[0] + rB[1] + rB[2] + rB[3]);
}

// ---------------------------------------------------------------------------
// K6: ktv[b,h,k,v] = sum_n exp(kh-ls) * vh, split over 8 N-chunks, atomicAdd.
// 576 threads: one (k,v) pair each.
// ---------------------------------------------------------------------------
__global__ __launch_bounds__(576) void k_ktv(const float* __restrict__ xc,
                                             const float* __restrict__ ls,
                                             float* __restrict__ ktv)
{
  __shared__ float pb[24][65];
  __shared__ float vb[24][65];
  __shared__ float lsl[24];
  const int nc = blockIdx.x, h = blockIdx.y, b = blockIdx.z;
  const int t = threadIdx.x;
  if (t < 24) lsl[t] = ls[(b * 8 + h) * 24 + t];
  __syncthreads();
  const int kk = t / 24, vv = t % 24;
  const float* kbase = xc + (size_t)((8 + b) * 192 + h * 24) * Nn;
  const float* vbase = xc + (size_t)((16 + b) * 192 + h * 24) * Nn;
  const int nb0 = nc * 512;
  float accv = 0.f;
  for (int sub = 0; sub < 8; ++sub) {
    int nbase = nb0 + sub * 64;
    for (int e = t; e < 1536; e += 576) {
      int ch = e >> 6, n = e & 63;
      pb[ch][n] = __expf(kbase[(size_t)ch * Nn + nbase + n] - lsl[ch]);
      vb[ch][n] = vbase[(size_t)ch * Nn + nbase + n];
    }
    __syncthreads();
    float a = 0.f;
#pragma unroll 16
    for (int i = 0; i < 64; ++i) a += pb[kk][i] * vb[vv][i];
    accv += a;
    __syncthreads();
  }
  atomicAdd(&ktv[((b * 8 + h) * 24 + kk) * 24 + vv], accv);
}

// ---------------------------------------------------------------------------
// K8: assemble cat[b][n][0:192] = scale*(q@ktv) + q*conv_v ; [192:256]=x_agg0
// ---------------------------------------------------------------------------
__global__ __launch_bounds__(256) void k_cat(
    const float* __restrict__ xc, const float* __restrict__ conv_v,
    const float* __restrict__ ktv, const float* __restrict__ x_agg0,
    float* __restrict__ cat)
{
  __shared__ float kt[4608];
  const int t = threadIdx.x;
  const int b = blockIdx.y;
  for (int e = t; e < 4608; e += 256) kt[e] = ktv[b * 4608 + e];
  __syncthreads();
  const int nl = t & 63;
  const int grp = t >> 6;
  const int n = blockIdx.x * 64 + nl;
  const float scale = 0.17677669529663687f;   // 32^-0.5
#pragma unroll
  for (int hh = 0; hh < 2; ++hh) {
    const int h = grp * 2 + hh;
    const float* qb = xc + (size_t)(b * 192 + h * 24) * Nn + n;
    float q[24];
#pragma unroll
    for (int c = 0; c < 24; ++c) q[c] = qb[(size_t)c * Nn];
    float ev[24];
#pragma unroll
    for (int v = 0; v < 24; ++v) ev[v] = 0.f;
    const float* kth = kt + h * 576;
#pragma unroll
    for (int k = 0; k < 24; ++k) {
      const float qk = q[k];
#pragma unroll
      for (int v = 0; v < 24; ++v) ev[v] += qk * kth[k * 24 + v];
    }
    const float* cvb = conv_v + (size_t)(b * 192 + h * 24) * Nn + n;
    float* ob = cat + ((size_t)(b * 4096 + n)) * 256 + h * 24;
#pragma unroll
    for (int v4 = 0; v4 < 6; ++v4) {
      float4 o;
      o.x = scale * ev[v4 * 4 + 0] + q[v4 * 4 + 0] * cvb[(size_t)(v4 * 4 + 0) * Nn];
      o.y = scale * ev[v4 * 4 + 1] + q[v4 * 4 + 1] * cvb[(size_t)(v4 * 4 + 1) * Nn];
      o.z = scale * ev[v4 * 4 + 2] + q[v4 * 4 + 2] * cvb[(size_t)(v4 * 4 + 2) * Nn];
      o.w = scale * ev[v4 * 4 + 3] + q[v4 * 4 + 3] * cvb[(size_t)(v4 * 4 + 3) * Nn];
      *(float4*)(ob + v4 * 4) = o;
    }
  }
  const float* xa = x_agg0 + ((size_t)(b * 4096 + blockIdx.x * 64)) * 64;
  float* cb = cat + ((size_t)(b * 4096 + blockIdx.x * 64)) * 256 + 192;
  for (int e2 = t; e2 < 4096; e2 += 256) {
    int nn = e2 >> 6, cc = e2 & 63;
    cb[(size_t)nn * 256 + cc] = xa[(size_t)nn * 64 + cc];
  }
}

// ---------------------------------------------------------------------------
// K9: out[m][c] = sum_k cat[m][k]*proj_w[c][k] + proj_b[c], in-place (io=cat=out).
// Tile 64m x 256c (full c in one block -> rows exclusive, safe in-place).
// ---------------------------------------------------------------------------
__global__ __launch_bounds__(256) void k_proj(float* __restrict__ io,
                                              const float* __restrict__ pw,
                                              const float* __restrict__ pb)
{
  __shared__ float Al[16][64];
  __shared__ float Wl[16][256];
  const int t = threadIdx.x;
  const int m0 = blockIdx.x * 64;
  const int tc = (t & 31) * 4;
  const int tm = (t >> 5) * 8;
  float acc[8][8];
#pragma unroll
  for (int i = 0; i < 8; ++i)
#pragma unroll
    for (int j = 0; j < 8; ++j) acc[i][j] = 0.f;

  for (int kc = 0; kc < 256; kc += 16) {
    {
      int row = t & 63, k0 = (t >> 6) << 2;
      float4 a = *(const float4*)(io + (size_t)(m0 + row) * 256 + kc + k0);
      Al[k0 + 0][row] = a.x; Al[k0 + 1][row] = a.y;
      Al[k0 + 2][row] = a.z; Al[k0 + 3][row] = a.w;
    }
#pragma unroll
    for (int i = 0; i < 4; ++i) {
      int e = t + i * 256;                // < 1024
      int c = e & 255, k4 = (e >> 8) << 2;
      float4 w = *(const float4*)(pw + (size_t)c * 256 + kc + k4);
      Wl[k4 + 0][c] = w.x; Wl[k4 + 1][c] = w.y;
      Wl[k4 + 2][c] = w.z; Wl[k4 + 3][c] = w.w;
    }
    __syncthreads();
#pragma unroll
    for (int k = 0; k < 16; ++k) {
      const float4 a0 = *(const float4*)&Al[k][tm];
      const float4 a1 = *(const float4*)&Al[k][tm + 4];
      const float4 w0 = *(const float4*)&Wl[k][tc];
      const float4 w1 = *(const float4*)&Wl[k][128 + tc];
      const float av[8] = {a0.x, a0.y, a0.z, a0.w, a1.x, a1.y, a1.z, a1.w};
      const float wv[8] = {w0.x, w0.y, w0.z, w0.w, w1.x, w1.y, w1.z, w1.w};
#pragma unroll
      for (int i = 0; i < 8; ++i)
#pragma unroll
        for (int j = 0; j < 8; ++j) acc[i][j] += av[i] * wv[j];
    }
    __syncthreads();
  }
  const float4 pb0 = *(const float4*)(pb + tc);
  const float4 pb1 = *(const float4*)(pb + 128 + tc);
#pragma unroll
  for (int i = 0; i < 8; ++i) {
    float4 o0 = make_float4(acc[i][0] + pb0.x, acc[i][1] + pb0.y,
                            acc[i][2] + pb0.z, acc[i][3] + pb0.w);
    float4 o1 = make_float4(acc[i][4] + pb1.x, acc[i][5] + pb1.y,
                            acc[i][6] + pb1.z, acc[i][7] + pb1.w);
    *(float4*)(io + (size_t)(m0 + tm + i) * 256 + tc) = o0;
    *(float4*)(io + (size_t)(m0 + tm + i) * 256 + 128 + tc) = o1;
  }
}

// ---------------------------------------------------------------------------
extern "C" void kernel_launch(void* const* d_in, const int* in_sizes, int n_in,
                              void* d_out, int out_size, void* d_ws, size_t ws_size,
                              hipStream_t stream)
{
  const float* x       = (const float*)d_in[0];
  const float* seg     = (const float*)d_in[1];
  const float* kv_w    = (const float*)d_in[2];
  const float* q_w     = (const float*)d_in[3];
  const float* proj_w  = (const float*)d_in[4];
  const float* proj_b  = (const float*)d_in[5];
  const float* agg0_dw = (const float*)d_in[6];
  const float* agg0_pw = (const float*)d_in[7];
  const float* ln_g    = (const float*)d_in[8];
  const float* ln_b    = (const float*)d_in[9];
  const float* agg1_dw = (const float*)d_in[10];
  const float* agg1_pw = (const float*)d_in[11];
  const float* bn1_g   = (const float*)d_in[12];
  const float* bn1_b   = (const float*)d_in[13];
  const float* bn1_m   = (const float*)d_in[14];
  const float* bn1_v   = (const float*)d_in[15];
  const float* agg2_dw = (const float*)d_in[16];
  const float* agg2_pw = (const float*)d_in[17];
  const float* bn2_g   = (const float*)d_in[18];
  const float* bn2_b   = (const float*)d_in[19];
  const float* bn2_m   = (const float*)d_in[20];
  const float* bn2_v   = (const float*)d_in[21];
  const float* agg3_dw = (const float*)d_in[22];
  const float* agg3_pw = (const float*)d_in[23];
  const float* bn3_g   = (const float*)d_in[24];
  const float* bn3_b   = (const float*)d_in[25];
  const float* bn3_m   = (const float*)d_in[26];
  const float* bn3_v   = (const float*)d_in[27];
  const float* crpe_w3 = (const float*)d_in[28];
  const float* crpe_b3 = (const float*)d_in[29];
  const float* crpe_w5 = (const float*)d_in[30];
  const float* crpe_b5 = (const float*)d_in[31];
  const float* crpe_w7 = (const float*)d_in[32];
  const float* crpe_b7 = (const float*)d_in[33];

  float* ws = (float*)d_ws;
  float* qkv    = ws;                         // 25165824 f  (reused as xc)
  float* xcbuf  = ws;
  float* dwout  = ws + 25165824;              // 18874368 f  (reused as conv_v)
  float* conv_v = dwout;
  float* dwout0 = ws + 25165824 + 18874368;   // 6291456 f
  float* x_agg0 = dwout0 + 6291456;           // 2097152 f
  float* ls     = x_agg0 + 2097152;           // 1536 f
  float* ktv    = ls + 1536;                  // 36864 f
  float* cat    = (float*)d_out;              // 8388608 f, proj runs in-place

  hipMemsetAsync(ktv, 0, 36864 * sizeof(float), stream);

  k_qkv<<<dim3(32, 2, 24), 256, 0, stream>>>(x, seg, kv_w, q_w, qkv);
  k_dw<<<dim3(6144), 256, 0, stream>>>(qkv, agg1_dw, agg2_dw, agg3_dw, agg0_dw,
                                       dwout, dwout0);
  k_pw_bn<<<dim3(32, 3, 24), 256, 0, stream>>>(
      dwout, agg1_pw, agg2_pw, agg3_pw,
      bn1_g, bn1_b, bn1_m, bn1_v,
      bn2_g, bn2_b, bn2_m, bn2_v,
      bn3_g, bn3_b, bn3_m, bn3_v, xcbuf);
  k_pw_ln<<<dim3(32, 8), 256, 0, stream>>>(dwout0, agg0_pw, ln_g, ln_b, x_agg0);
  k_sm<<<dim3(1536), 256, 0, stream>>>(xcbuf, ls);
  k_ktv<<<dim3(8, 8, 8), 576, 0, stream>>>(xcbuf, ls, ktv);
  k_crpe<<<dim3(1536), 256, 0, stream>>>(xcbuf, crpe_w3, crpe_b3, crpe_w5,
                                         crpe_b5, crpe_w7, crpe_b7, conv_v);
  k_cat<<<dim3(64, 8), 256, 0, stream>>>(xcbuf, conv_v, ktv, x_agg0, cat);
  k_proj<<<dim3(512), 256, 0, stream>>>(cat, proj_w, proj_b);
}

// Round 2
// 400.195 us; speedup vs baseline: 1.3974x; 1.3974x over previous
//
#include <hip/hip_runtime.h>
#include <math.h>

#define DI __device__ __forceinline__

typedef unsigned short u16;
typedef __attribute__((ext_vector_type(8))) short bf16x8;
typedef __attribute__((ext_vector_type(4))) float f32x4;

static constexpr int Cc = 256;
static constexpr int Nn = 4096;   // 64*64 spatial

DI float hswish(float v) { return v * fminf(fmaxf(v + 3.f, 0.f), 6.f) * (1.f / 6.f); }

DI u16 f2b(float f) {
  union { float f; unsigned int u; } c; c.f = f;
  return (u16)((c.u + 0x7FFFu + ((c.u >> 16) & 1u)) >> 16);
}

typedef const __attribute__((address_space(1))) unsigned int* gas1_t;
typedef __attribute__((address_space(3))) unsigned int* las3_t;
DI void gld16(const void* g, void* l) {
  __builtin_amdgcn_global_load_lds((gas1_t)g, (las3_t)l, 16, 0, 0);
}

// ---------------------------------------------------------------------------
// K0: f32 -> bf16 conversion of x, seg, kv_w, q_w, proj_w.
// ---------------------------------------------------------------------------
__global__ __launch_bounds__(256) void k_cvt(
    const float4* __restrict__ x, const float4* __restrict__ seg,
    const float4* __restrict__ kvw, const float4* __restrict__ qw,
    const float4* __restrict__ pw,
    ushort4* __restrict__ xb, ushort4* __restrict__ segb,
    ushort4* __restrict__ kvwb, ushort4* __restrict__ qwb,
    ushort4* __restrict__ pwb)
{
  const int total = 4259840;            // float4 units
  for (int i = blockIdx.x * 256 + threadIdx.x; i < total; i += gridDim.x * 256) {
    const float4* s; ushort4* d; int j;
    if (i < 2097152)      { s = x;   d = xb;   j = i; }
    else if (i < 4194304) { s = seg; d = segb; j = i - 2097152; }
    else if (i < 4227072) { s = kvw; d = kvwb; j = i - 4194304; }
    else if (i < 4243456) { s = qw;  d = qwb;  j = i - 4227072; }
    else                  { s = pw;  d = pwb;  j = i - 4243456; }
    float4 v = s[j];
    ushort4 o;
    o.x = f2b(v.x); o.y = f2b(v.y); o.z = f2b(v.z); o.w = f2b(v.w);
    d[j] = o;
  }
}

// ---------------------------------------------------------------------------
// K1: qkv gemm via bf16 MFMA. Out[g][c][n] = sum_k Wg[c][k] * In[n][k], f32 out.
// Block 256 thr (4 waves), tile 128c x 128n, K-step 32, double-buffered LDS in
// fragment order: [sub(16rows)][lane][8 bf16]; staged by global_load_lds with
// per-lane pre-swizzled global addresses (LDS dest is linear, m104/m173).
// Wave quadrants 64c x 64n; acc 4x4 f32x4.
// MFMA A frag: A[lane&15][(lane>>4)*8+j]; B frag: B[(lane>>4)*8+j][lane&15];
// D: col=lane&15, row=(lane>>4)*4+reg (m89).
// ---------------------------------------------------------------------------
__global__ __launch_bounds__(256) void k_qkv(
    const u16* __restrict__ xb, const u16* __restrict__ segb,
    const u16* __restrict__ kvwb, const u16* __restrict__ qwb,
    float* __restrict__ qkv)
{
  __shared__ __align__(16) u16 As[2][4096];   // 8 subs * 64 lanes * 8
  __shared__ __align__(16) u16 Bs[2][4096];
  const int t = threadIdx.x;
  const int lane = t & 63, wave = t >> 6;
  const int n0 = blockIdx.x * 128;
  const int c0 = blockIdx.y * 128;
  const int g  = blockIdx.z;
  const int grp = g >> 3, b = g & 7;
  const u16* __restrict__ In = (grp == 0 ? segb : xb) + (size_t)b * Nn * Cc;
  const u16* __restrict__ Wg = (grp == 0) ? qwb : (kvwb + (grp == 2 ? Cc * Cc : 0));

  const int rA = lane & 15;          // row within 16-row subtile
  const int kA = (lane >> 4) * 8;    // k offset within 32-k step
  const int s0 = wave * 2, s1 = wave * 2 + 1;

#define STAGE(buf, k0)                                                        \
  {                                                                           \
    gld16(Wg + (size_t)(c0 + s0 * 16 + rA) * Cc + (k0) + kA, &As[buf][s0 * 512]); \
    gld16(In + (size_t)(n0 + s0 * 16 + rA) * Cc + (k0) + kA, &Bs[buf][s0 * 512]); \
    gld16(Wg + (size_t)(c0 + s1 * 16 + rA) * Cc + (k0) + kA, &As[buf][s1 * 512]); \
    gld16(In + (size_t)(n0 + s1 * 16 + rA) * Cc + (k0) + kA, &Bs[buf][s1 * 512]); \
  }

  f32x4 acc[4][4];
#pragma unroll
  for (int m = 0; m < 4; ++m)
#pragma unroll
    for (int n = 0; n < 4; ++n) acc[m][n] = (f32x4){0.f, 0.f, 0.f, 0.f};

  const int asub = (wave >> 1) * 4;   // c quadrant subtiles
  const int bsub = (wave & 1) * 4;    // n quadrant subtiles

  STAGE(0, 0);
  for (int ks = 0; ks < 8; ++ks) {
    __syncthreads();
    if (ks < 7) STAGE((ks + 1) & 1, (ks + 1) * 32);
    const int cur = ks & 1;
    bf16x8 af[4], bfr[4];
#pragma unroll
    for (int m = 0; m < 4; ++m)
      af[m] = *(const bf16x8*)&As[cur][(asub + m) * 512 + lane * 8];
#pragma unroll
    for (int n = 0; n < 4; ++n)
      bfr[n] = *(const bf16x8*)&Bs[cur][(bsub + n) * 512 + lane * 8];
#pragma unroll
    for (int m = 0; m < 4; ++m)
#pragma unroll
      for (int n = 0; n < 4; ++n)
        acc[m][n] = __builtin_amdgcn_mfma_f32_16x16x32_bf16(af[m], bfr[n], acc[m][n], 0, 0, 0);
  }
#undef STAGE

  const int wc = (wave >> 1) * 64, wn = (wave & 1) * 64;
  const int row4 = (lane >> 4) * 4, col = lane & 15;
  float* __restrict__ op = qkv + (size_t)(g * Cc + c0 + wc) * Nn + n0 + wn;
#pragma unroll
  for (int m = 0; m < 4; ++m)
#pragma unroll
    for (int nn = 0; nn < 4; ++nn)
#pragma unroll
      for (int r = 0; r < 4; ++r)
        op[(size_t)(m * 16 + row4 + r) * Nn + nn * 16 + col] = acc[m][nn][r];
}

// ---------------------------------------------------------------------------
// Depthwise conv on one 64x64 plane staged in zero-padded LDS (pad 3).
// ---------------------------------------------------------------------------
template <int KS>
DI void dw_plane(const float* __restrict__ sp, const float* __restrict__ wl,
                 float* __restrict__ dst, float bias, int t)
{
  constexpr int P = KS / 2;
  float wr[KS * KS];
#pragma unroll
  for (int i = 0; i < KS * KS; ++i) wr[i] = wl[i];
  const int x = t & 63;
  const int yb = (t >> 6) << 4;
  float acc[16];
#pragma unroll
  for (int i = 0; i < 16; ++i) acc[i] = bias;
#pragma unroll
  for (int r = 0; r < 16 + 2 * P; ++r) {
    float v[KS];
    const float* rp = sp + (yb + r + (3 - P)) * 70 + x + (3 - P);
#pragma unroll
    for (int dx = 0; dx < KS; ++dx) v[dx] = rp[dx];
#pragma unroll
    for (int dy = 0; dy < KS; ++dy) {
      const int yl = r - dy;
      if (yl >= 0 && yl < 16) {
        float s = acc[yl];
#pragma unroll
        for (int dx = 0; dx < KS; ++dx) s += wr[dy * KS + dx] * v[dx];
        acc[yl] = s;
      }
    }
  }
#pragma unroll
  for (int yl = 0; yl < 16; ++yl) dst[(yb + yl) * 64 + x] = acc[yl];
}

// K2: all depthwise convs feeding the pw stages.
__global__ __launch_bounds__(256) void k_dw(
    const float* __restrict__ qkv,
    const float* __restrict__ a1w, const float* __restrict__ a2w,
    const float* __restrict__ a3w, const float* __restrict__ a0w,
    float* __restrict__ dwout, float* __restrict__ dwout0)
{
  __shared__ float sp[70 * 70];
  __shared__ float wl[49];
  const int t = threadIdx.x;
  const int p = blockIdx.x;
  const float* src; float* dst; const float* wsp; int ks;
  if (p < 4608) {
    int g = p / 192, c = p % 192, r = c >> 6;
    ks = 3 + 2 * r;
    wsp = (r == 0 ? a1w : (r == 1 ? a2w : a3w)) + (c & 63) * ks * ks;
    src = qkv + (size_t)(g * 256 + c) * Nn;
    dst = dwout + (size_t)p * Nn;
  } else {
    int q = p - 4608;
    int b = q / 192, j = q % 192;
    ks = 3;
    wsp = a0w + j * 9;
    src = qkv + (size_t)(((j >> 6) * 8 + b) * 256 + 192 + (j & 63)) * Nn;
    dst = dwout0 + (size_t)q * Nn;
  }
  for (int i = t; i < 4900; i += 256) sp[i] = 0.f;
  if (t < 49) wl[t] = (t < ks * ks) ? wsp[t] : 0.f;
  __syncthreads();
#pragma unroll
  for (int i = 0; i < 16; ++i) {
    int e = t + i * 256;
    sp[((e >> 6) + 3) * 70 + (e & 63) + 3] = src[e];
  }
  __syncthreads();
  if (ks == 3)      dw_plane<3>(sp, wl, dst, 0.f, t);
  else if (ks == 5) dw_plane<5>(sp, wl, dst, 0.f, t);
  else              dw_plane<7>(sp, wl, dst, 0.f, t);
}

// K7: crpe depthwise convs on the V images with bias.
__global__ __launch_bounds__(256) void k_crpe(
    const float* __restrict__ xc,
    const float* __restrict__ w3, const float* __restrict__ b3,
    const float* __restrict__ w5, const float* __restrict__ b5,
    const float* __restrict__ w7, const float* __restrict__ b7,
    float* __restrict__ conv_v)
{
  __shared__ float sp[70 * 70];
  __shared__ float wl[49];
  const int t = threadIdx.x;
  const int p = blockIdx.x;               // b*192 + ch
  const int b = p / 192, ch = p % 192;
  const float* wsp; float bias; int ks;
  if (ch < 48)       { ks = 3; wsp = w3 + ch * 9;          bias = b3[ch]; }
  else if (ch < 120) { ks = 5; wsp = w5 + (ch - 48) * 25;  bias = b5[ch - 48]; }
  else               { ks = 7; wsp = w7 + (ch - 120) * 49; bias = b7[ch - 120]; }
  const float* src = xc + (size_t)((16 + b) * 192 + ch) * Nn;
  float* dst = conv_v + (size_t)p * Nn;
  for (int i = t; i < 4900; i += 256) sp[i] = 0.f;
  if (t < 49) wl[t] = (t < ks * ks) ? wsp[t] : 0.f;
  __syncthreads();
#pragma unroll
  for (int i = 0; i < 16; ++i) {
    int e = t + i * 256;
    sp[((e >> 6) + 3) * 70 + (e & 63) + 3] = src[e];
  }
  __syncthreads();
  if (ks == 3)      dw_plane<3>(sp, wl, dst, bias, t);
  else if (ks == 5) dw_plane<5>(sp, wl, dst, bias, t);
  else              dw_plane<7>(sp, wl, dst, bias, t);
}

// ---------------------------------------------------------------------------
// K3: pointwise 64->64 + batchnorm + hardswish -> xc[g][r*64+co][n]
// ---------------------------------------------------------------------------
__global__ __launch_bounds__(256) void k_pw_bn(
    const float* __restrict__ dwout,
    const float* __restrict__ w1, const float* __restrict__ w2, const float* __restrict__ w3,
    const float* __restrict__ g1, const float* __restrict__ be1, const float* __restrict__ m1, const float* __restrict__ v1,
    const float* __restrict__ g2, const float* __restrict__ be2, const float* __restrict__ m2, const float* __restrict__ v2,
    const float* __restrict__ g3, const float* __restrict__ be3, const float* __restrict__ m3, const float* __restrict__ v3,
    float* __restrict__ xc)
{
  __shared__ float Tl[64][128];
  __shared__ float Wt[64][64];
  const int t = threadIdx.x;
  const int n0 = blockIdx.x * 128;
  const int r = blockIdx.y;
  const int g = blockIdx.z;
  const float* Wp = (r == 0 ? w1 : (r == 1 ? w2 : w3));
  const float* bg = (r == 0 ? g1 : (r == 1 ? g2 : g3));
  const float* bb = (r == 0 ? be1 : (r == 1 ? be2 : be3));
  const float* bm = (r == 0 ? m1 : (r == 1 ? m2 : m3));
  const float* bv = (r == 0 ? v1 : (r == 1 ? v2 : v3));
  const size_t ibase = (size_t)(g * 192 + r * 64) * Nn + n0;
#pragma unroll
  for (int i = 0; i < 8; ++i) {
    int e = t + i * 256;
    int ci = e >> 5, nf = (e & 31) * 4;
    *(float4*)&Tl[ci][nf] = *(const float4*)(dwout + ibase + (size_t)ci * Nn + nf);
  }
#pragma unroll
  for (int i = 0; i < 16; ++i) {
    int e = t + i * 256;
    int co = e & 63, ci = e >> 6;
    Wt[ci][co] = Wp[co * 64 + ci];
  }
  __syncthreads();
  const int tn = (t & 15) * 4;
  const int tc = (t >> 4) * 4;
  float acc[4][8];
#pragma unroll
  for (int i = 0; i < 4; ++i)
#pragma unroll
    for (int j = 0; j < 8; ++j) acc[i][j] = 0.f;
#pragma unroll 8
  for (int ci = 0; ci < 64; ++ci) {
    const float4 i0 = *(const float4*)&Tl[ci][tn];
    const float4 i1 = *(const float4*)&Tl[ci][64 + tn];
    const float4 wv = *(const float4*)&Wt[ci][tc];
    const float iv[8] = {i0.x, i0.y, i0.z, i0.w, i1.x, i1.y, i1.z, i1.w};
    const float wa[4] = {wv.x, wv.y, wv.z, wv.w};
#pragma unroll
    for (int i = 0; i < 4; ++i)
#pragma unroll
      for (int j = 0; j < 8; ++j) acc[i][j] += wa[i] * iv[j];
  }
  const size_t obase = (size_t)(g * 192 + r * 64 + tc) * Nn + n0;
#pragma unroll
  for (int i = 0; i < 4; ++i) {
    int co = tc + i;
    float sc = bg[co] * rsqrtf(bv[co] + 1e-5f);
    float sh = bb[co] - bm[co] * sc;
    float4 o0, o1;
    o0.x = hswish(acc[i][0] * sc + sh); o0.y = hswish(acc[i][1] * sc + sh);
    o0.z = hswish(acc[i][2] * sc + sh); o0.w = hswish(acc[i][3] * sc + sh);
    o1.x = hswish(acc[i][4] * sc + sh); o1.y = hswish(acc[i][5] * sc + sh);
    o1.z = hswish(acc[i][6] * sc + sh); o1.w = hswish(acc[i][7] * sc + sh);
    *(float4*)(xc + obase + (size_t)i * Nn + tn) = o0;
    *(float4*)(xc + obase + (size_t)i * Nn + 64 + tn) = o1;
  }
}

// ---------------------------------------------------------------------------
// K4: agg0 pointwise 192->64 + layernorm(64 ch) + hardswish -> x_agg0[b][n][co]
// ---------------------------------------------------------------------------
__global__ __launch_bounds__(256) void k_pw_ln(
    const float* __restrict__ dwout0, const float* __restrict__ pw,
    const float* __restrict__ lng, const float* __restrict__ lnb,
    float* __restrict__ x_agg0)
{
  __shared__ float Tl[64][128];
  __shared__ float Wt[64][64];
  const int t = threadIdx.x;
  const int n0 = blockIdx.x * 128;
  const int b = blockIdx.y;
  const int tn = (t & 15) * 4;
  const int tc = (t >> 4) * 4;
  float acc[4][8];
#pragma unroll
  for (int i = 0; i < 4; ++i)
#pragma unroll
    for (int j = 0; j < 8; ++j) acc[i][j] = 0.f;

  for (int kc = 0; kc < 192; kc += 64) {
#pragma unroll
    for (int i = 0; i < 8; ++i) {
      int e = t + i * 256;
      int ci = e >> 5, nf = (e & 31) * 4;
      *(float4*)&Tl[ci][nf] =
          *(const float4*)(dwout0 + (size_t)(b * 192 + kc + ci) * Nn + n0 + nf);
    }
#pragma unroll
    for (int i = 0; i < 16; ++i) {
      int e = t + i * 256;
      int co = e & 63, ci = e >> 6;
      Wt[ci][co] = pw[co * 192 + kc + ci];
    }
    __syncthreads();
#pragma unroll 8
    for (int ci = 0; ci < 64; ++ci) {
      const float4 i0 = *(const float4*)&Tl[ci][tn];
      const float4 i1 = *(const float4*)&Tl[ci][64 + tn];
      const float4 wv = *(const float4*)&Wt[ci][tc];
      const float iv[8] = {i0.x, i0.y, i0.z, i0.w, i1.x, i1.y, i1.z, i1.w};
      const float wa[4] = {wv.x, wv.y, wv.z, wv.w};
#pragma unroll
      for (int i = 0; i < 4; ++i)
#pragma unroll
        for (int j = 0; j < 8; ++j) acc[i][j] += wa[i] * iv[j];
    }
    __syncthreads();
  }
  float* redS = &Tl[0][0];
  float* redQ = &Tl[0][0] + 2048;
  float* muA = &Tl[0][0] + 4096;
  float* isA = &Tl[0][0] + 4224;
#pragma unroll
  for (int j = 0; j < 8; ++j) {
    int nl = (j < 4) ? (tn + j) : (64 + tn + j - 4);
    float s = acc[0][j] + acc[1][j] + acc[2][j] + acc[3][j];
    float q = acc[0][j] * acc[0][j] + acc[1][j] * acc[1][j] +
              acc[2][j] * acc[2][j] + acc[3][j] * acc[3][j];
    redS[(t >> 4) * 128 + nl] = s;
    redQ[(t >> 4) * 128 + nl] = q;
  }
  __syncthreads();
  if (t < 128) {
    float s = 0.f, q = 0.f;
#pragma unroll
    for (int rr = 0; rr < 16; ++rr) { s += redS[rr * 128 + t]; q += redQ[rr * 128 + t]; }
    float mu = s * (1.f / 64.f);
    float var = q * (1.f / 64.f) - mu * mu;
    muA[t] = mu;
    isA[t] = rsqrtf(var + 1e-5f);
  }
  __syncthreads();
  float lg[4], lb[4];
#pragma unroll
  for (int i = 0; i < 4; ++i) { lg[i] = lng[tc + i]; lb[i] = lnb[tc + i]; }
#pragma unroll
  for (int j = 0; j < 8; ++j) {
    int nl = (j < 4) ? (tn + j) : (64 + tn + j - 4);
    float mu = muA[nl], is = isA[nl];
    float4 o;
    o.x = hswish((acc[0][j] - mu) * is * lg[0] + lb[0]);
    o.y = hswish((acc[1][j] - mu) * is * lg[1] + lb[1]);
    o.z = hswish((acc[2][j] - mu) * is * lg[2] + lb[2]);
    o.w = hswish((acc[3][j] - mu) * is * lg[3] + lb[3]);
    *(float4*)(x_agg0 + (size_t)((b << 12) + n0 + nl) * 64 + tc) = o;
  }
}

// ---------------------------------------------------------------------------
// K5: per-(b,h,c) softmax stats over N: ls = max + log(sum(exp(x-max)))
// ---------------------------------------------------------------------------
__global__ __launch_bounds__(256) void k_sm(const float* __restrict__ xc,
                                            float* __restrict__ ls)
{
  __shared__ float rA[4], rB[4];
  const int rho = blockIdx.x;             // b*192 + h*24 + c
  const int b = rho / 192, rem = rho % 192;
  const float* row = xc + (size_t)((8 + b) * 192 + rem) * Nn;
  const int t = threadIdx.x;
  float v[16];
#pragma unroll
  for (int i = 0; i < 16; ++i) v[i] = row[t + i * 256];
  float m = v[0];
#pragma unroll
  for (int i = 1; i < 16; ++i) m = fmaxf(m, v[i]);
#pragma unroll
  for (int off = 32; off > 0; off >>= 1) m = fmaxf(m, __shfl_xor(m, off, 64));
  if ((t & 63) == 0) rA[t >> 6] = m;
  __syncthreads();
  m = fmaxf(fmaxf(rA[0], rA[1]), fmaxf(rA[2], rA[3]));
  float s = 0.f;
#pragma unroll
  for (int i = 0; i < 16; ++i) s += __expf(v[i] - m);
#pragma unroll
  for (int off = 32; off > 0; off >>= 1) s += __shfl_xor(s, off, 64);
  if ((t & 63) == 0) rB[t >> 6] = s;
  __syncthreads();
  if (t == 0) ls[rho] = m + __logf(rB[0] + rB[1] + rB[2] + rB[3]);
}

// ---------------------------------------------------------------------------
// K6: ktv[b,h,k,v] = sum_n exp(kh-ls) * vh, 8 N-chunks, atomicAdd.
// ---------------------------------------------------------------------------
__global__ __launch_bounds__(576) void k_ktv(const float* __restrict__ xc,
                                             const float* __restrict__ ls,
                                             float* __restrict__ ktv)
{
  __shared__ float pb[24][65];
  __shared__ float vb[24][65];
  __shared__ float lsl[24];
  const int nc = blockIdx.x, h = blockIdx.y, b = blockIdx.z;
  const int t = threadIdx.x;
  if (t < 24) lsl[t] = ls[(b * 8 + h) * 24 + t];
  __syncthreads();
  const int kk = t / 24, vv = t % 24;
  const float* kbase = xc + (size_t)((8 + b) * 192 + h * 24) * Nn;
  const float* vbase = xc + (size_t)((16 + b) * 192 + h * 24) * Nn;
  const int nb0 = nc * 512;
  float accv = 0.f;
  for (int sub = 0; sub < 8; ++sub) {
    int nbase = nb0 + sub * 64;
    for (int e = t; e < 1536; e += 576) {
      int ch = e >> 6, n = e & 63;
      pb[ch][n] = __expf(kbase[(size_t)ch * Nn + nbase + n] - lsl[ch]);
      vb[ch][n] = vbase[(size_t)ch * Nn + nbase + n];
    }
    __syncthreads();
    float a = 0.f;
#pragma unroll 16
    for (int i = 0; i < 64; ++i) a += pb[kk][i] * vb[vv][i];
    accv += a;
    __syncthreads();
  }
  atomicAdd(&ktv[((b * 8 + h) * 24 + kk) * 24 + vv], accv);
}

// ---------------------------------------------------------------------------
// K8: assemble cat (bf16) [b][n][0:192] = scale*(q@ktv)+q*conv_v; [192:256]=x_agg0
// ---------------------------------------------------------------------------
__global__ __launch_bounds__(256) void k_cat(
    const float* __restrict__ xc, const float* __restrict__ conv_v,
    const float* __restrict__ ktv, const float* __restrict__ x_agg0,
    u16* __restrict__ catb)
{
  __shared__ float kt[4608];
  const int t = threadIdx.x;
  const int b = blockIdx.y;
  for (int e = t; e < 4608; e += 256) kt[e] = ktv[b * 4608 + e];
  __syncthreads();
  const int nl = t & 63;
  const int grp = t >> 6;
  const int n = blockIdx.x * 64 + nl;
  const float scale = 0.17677669529663687f;   // 32^-0.5
#pragma unroll
  for (int hh = 0; hh < 2; ++hh) {
    const int h = grp * 2 + hh;
    const float* qb = xc + (size_t)(b * 192 + h * 24) * Nn + n;
    float q[24];
#pragma unroll
    for (int c = 0; c < 24; ++c) q[c] = qb[(size_t)c * Nn];
    float ev[24];
#pragma unroll
    for (int v = 0; v < 24; ++v) ev[v] = 0.f;
    const float* kth = kt + h * 576;
#pragma unroll
    for (int k = 0; k < 24; ++k) {
      const float qk = q[k];
#pragma unroll
      for (int v = 0; v < 24; ++v) ev[v] += qk * kth[k * 24 + v];
    }
    const float* cvb = conv_v + (size_t)(b * 192 + h * 24) * Nn + n;
    u16* ob = catb + ((size_t)(b * 4096 + n)) * 256 + h * 24;
#pragma unroll
    for (int v4 = 0; v4 < 6; ++v4) {
      ushort4 o;
      o.x = f2b(scale * ev[v4 * 4 + 0] + q[v4 * 4 + 0] * cvb[(size_t)(v4 * 4 + 0) * Nn]);
      o.y = f2b(scale * ev[v4 * 4 + 1] + q[v4 * 4 + 1] * cvb[(size_t)(v4 * 4 + 1) * Nn]);
      o.z = f2b(scale * ev[v4 * 4 + 2] + q[v4 * 4 + 2] * cvb[(size_t)(v4 * 4 + 2) * Nn]);
      o.w = f2b(scale * ev[v4 * 4 + 3] + q[v4 * 4 + 3] * cvb[(size_t)(v4 * 4 + 3) * Nn]);
      *(ushort4*)(ob + v4 * 4) = o;
    }
  }
  const float* xa = x_agg0 + ((size_t)(b * 4096 + blockIdx.x * 64)) * 64;
  u16* cb = catb + ((size_t)(b * 4096 + blockIdx.x * 64)) * 256 + 192;
  for (int e2 = t; e2 < 4096; e2 += 256) {
    int nn = e2 >> 6, cc = e2 & 63;
    cb[(size_t)nn * 256 + cc] = f2b(xa[(size_t)nn * 64 + cc]);
  }
}

// ---------------------------------------------------------------------------
// K9: out[m][c] = sum_k catb[m][k]*pwb[c][k] + pb[c]  (bf16 MFMA, f32 out)
// Same structure as k_qkv: tile 128m x 128c, grid (256, 2).
// ---------------------------------------------------------------------------
__global__ __launch_bounds__(256) void k_proj(
    const u16* __restrict__ catb, const u16* __restrict__ pwb,
    const float* __restrict__ pb, float* __restrict__ out)
{
  __shared__ __align__(16) u16 As[2][4096];
  __shared__ __align__(16) u16 Bs[2][4096];
  const int t = threadIdx.x;
  const int lane = t & 63, wave = t >> 6;
  const int m0 = blockIdx.x * 128;
  const int c0 = blockIdx.y * 128;
  const int rA = lane & 15;
  const int kA = (lane >> 4) * 8;
  const int s0 = wave * 2, s1 = wave * 2 + 1;

#define STAGE(buf, k0)                                                        \
  {                                                                           \
    gld16(catb + (size_t)(m0 + s0 * 16 + rA) * 256 + (k0) + kA, &As[buf][s0 * 512]); \
    gld16(pwb  + (size_t)(c0 + s0 * 16 + rA) * 256 + (k0) + kA, &Bs[buf][s0 * 512]); \
    gld16(catb + (size_t)(m0 + s1 * 16 + rA) * 256 + (k0) + kA, &As[buf][s1 * 512]); \
    gld16(pwb  + (size_t)(c0 + s1 * 16 + rA) * 256 + (k0) + kA, &Bs[buf][s1 * 512]); \
  }

  f32x4 acc[4][4];
#pragma unroll
  for (int m = 0; m < 4; ++m)
#pragma unroll
    for (int n = 0; n < 4; ++n) acc[m][n] = (f32x4){0.f, 0.f, 0.f, 0.f};

  const int asub = (wave >> 1) * 4;
  const int bsub = (wave & 1) * 4;

  STAGE(0, 0);
  for (int ks = 0; ks < 8; ++ks) {
    __syncthreads();
    if (ks < 7) STAGE((ks + 1) & 1, (ks + 1) * 32);
    const int cur = ks & 1;
    bf16x8 af[4], bfr[4];
#pragma unroll
    for (int m = 0; m < 4; ++m)
      af[m] = *(const bf16x8*)&As[cur][(asub + m) * 512 + lane * 8];
#pragma unroll
    for (int n = 0; n < 4; ++n)
      bfr[n] = *(const bf16x8*)&Bs[cur][(bsub + n) * 512 + lane * 8];
#pragma unroll
    for (int m = 0; m < 4; ++m)
#pragma unroll
      for (int n = 0; n < 4; ++n)
        acc[m][n] = __builtin_amdgcn_mfma_f32_16x16x32_bf16(af[m], bfr[n], acc[m][n], 0, 0, 0);
  }
#undef STAGE

  const int wm = (wave >> 1) * 64, wn = (wave & 1) * 64;
  const int row4 = (lane >> 4) * 4, col = lane & 15;
  float pbv[4];
#pragma unroll
  for (int nn = 0; nn < 4; ++nn) pbv[nn] = pb[c0 + wn + nn * 16 + col];
  float* __restrict__ op = out + (size_t)(m0 + wm) * 256 + c0 + wn;
#pragma unroll
  for (int mi = 0; mi < 4; ++mi)
#pragma unroll
    for (int nn = 0; nn < 4; ++nn)
#pragma unroll
      for (int r = 0; r < 4; ++r)
        op[(size_t)(mi * 16 + row4 + r) * 256 + nn * 16 + col] = acc[mi][nn][r] + pbv[nn];
}

// ---------------------------------------------------------------------------
extern "C" void kernel_launch(void* const* d_in, const int* in_sizes, int n_in,
                              void* d_out, int out_size, void* d_ws, size_t ws_size,
                              hipStream_t stream)
{
  const float* x       = (const float*)d_in[0];
  const float* seg     = (const float*)d_in[1];
  const float* kv_w    = (const float*)d_in[2];
  const float* q_w     = (const float*)d_in[3];
  const float* proj_w  = (const float*)d_in[4];
  const float* proj_b  = (const float*)d_in[5];
  const float* agg0_dw = (const float*)d_in[6];
  const float* agg0_pw = (const float*)d_in[7];
  const float* ln_g    = (const float*)d_in[8];
  const float* ln_b    = (const float*)d_in[9];
  const float* agg1_dw = (const float*)d_in[10];
  const float* agg1_pw = (const float*)d_in[11];
  const float* bn1_g   = (const float*)d_in[12];
  const float* bn1_b   = (const float*)d_in[13];
  const float* bn1_m   = (const float*)d_in[14];
  const float* bn1_v   = (const float*)d_in[15];
  const float* agg2_dw = (const float*)d_in[16];
  const float* agg2_pw = (const float*)d_in[17];
  const float* bn2_g   = (const float*)d_in[18];
  const float* bn2_b   = (const float*)d_in[19];
  const float* bn2_m   = (const float*)d_in[20];
  const float* bn2_v   = (const float*)d_in[21];
  const float* agg3_dw = (const float*)d_in[22];
  const float* agg3_pw = (const float*)d_in[23];
  const float* bn3_g   = (const float*)d_in[24];
  const float* bn3_b   = (const float*)d_in[25];
  const float* bn3_m   = (const float*)d_in[26];
  const float* bn3_v   = (const float*)d_in[27];
  const float* crpe_w3 = (const float*)d_in[28];
  const float* crpe_b3 = (const float*)d_in[29];
  const float* crpe_w5 = (const float*)d_in[30];
  const float* crpe_b5 = (const float*)d_in[31];
  const float* crpe_w7 = (const float*)d_in[32];
  const float* crpe_b7 = (const float*)d_in[33];

  float* ws = (float*)d_ws;
  float* qkv    = ws;                         // 25165824 f (reused as xc)
  float* xcbuf  = ws;
  float* dwout  = ws + 25165824;              // 18874368 f (reused: bf16 in, conv_v)
  float* conv_v = dwout;
  u16*   xb     = (u16*)(ws + 25165824);      // 8388608 bf16
  u16*   segb   = (u16*)(ws + 29360128);      // 8388608 bf16
  u16*   kvwb   = (u16*)(ws + 33554432);      // 131072 bf16
  u16*   qwb    = (u16*)(ws + 33619968);      // 65536 bf16
  float* dwout0 = ws + 44040192;              // 6291456 f (reused: catb)
  u16*   catb   = (u16*)(ws + 44040192);      // 8388608 bf16
  float* x_agg0 = ws + 50331648;              // 2097152 f
  float* ls     = ws + 52428800;              // 1536 f
  float* ktv    = ws + 52430336;              // 36864 f
  u16*   pwb    = (u16*)(ws + 52467200);      // 65536 bf16
  float* out    = (float*)d_out;

  hipMemsetAsync(ktv, 0, 36864 * sizeof(float), stream);

  k_cvt<<<dim3(1024), 256, 0, stream>>>(
      (const float4*)x, (const float4*)seg, (const float4*)kv_w,
      (const float4*)q_w, (const float4*)proj_w,
      (ushort4*)xb, (ushort4*)segb, (ushort4*)kvwb, (ushort4*)qwb, (ushort4*)pwb);
  k_qkv<<<dim3(32, 2, 24), 256, 0, stream>>>(xb, segb, kvwb, qwb, qkv);
  k_dw<<<dim3(6144), 256, 0, stream>>>(qkv, agg1_dw, agg2_dw, agg3_dw, agg0_dw,
                                       dwout, dwout0);
  k_pw_bn<<<dim3(32, 3, 24), 256, 0, stream>>>(
      dwout, agg1_pw, agg2_pw, agg3_pw,
      bn1_g, bn1_b, bn1_m, bn1_v,
      bn2_g, bn2_b, bn2_m, bn2_v,
      bn3_g, bn3_b, bn3_m, bn3_v, xcbuf);
  k_pw_ln<<<dim3(32, 8), 256, 0, stream>>>(dwout0, agg0_pw, ln_g, ln_b, x_agg0);
  k_sm<<<dim3(1536), 256, 0, stream>>>(xcbuf, ls);
  k_ktv<<<dim3(8, 8, 8), 576, 0, stream>>>(xcbuf, ls, ktv);
  k_crpe<<<dim3(1536), 256, 0, stream>>>(xcbuf, crpe_w3, crpe_b3, crpe_w5,
                                         crpe_b5, crpe_w7, crpe_b7, conv_v);
  k_cat<<<dim3(64, 8), 256, 0, stream>>>(xcbuf, conv_v, ktv, x_agg0, catb);
  k_proj<<<dim3(256, 2), 256, 0, stream>>>(catb, pwb, proj_b, out);
}

// Round 4
// 363.033 us; speedup vs baseline: 1.5404x; 1.1024x over previous
//
#include <hip/hip_runtime.h>

#define DI __device__ __forceinline__

typedef unsigned short u16;
typedef __attribute__((ext_vector_type(8))) short bf16x8;
typedef __attribute__((ext_vector_type(8))) unsigned short u16x8;
typedef __attribute__((ext_vector_type(4))) float f32x4;

static constexpr int Cc = 256;
static constexpr int Nn = 4096;   // 64*64 spatial

DI float hswish(float v) { return v * fminf(fmaxf(v + 3.f, 0.f), 6.f) * (1.f / 6.f); }

DI u16 f2b(float f) {
  union { float f; unsigned int u; } c; c.f = f;
  return (u16)((c.u + 0x7FFFu + ((c.u >> 16) & 1u)) >> 16);
}
DI float b2f(u16 v) {
  union { unsigned int u; float f; } c; c.u = ((unsigned int)v) << 16; return c.f;
}
DI u16x8 pack8(float4 a, float4 b) {
  u16x8 r;
  r[0] = f2b(a.x); r[1] = f2b(a.y); r[2] = f2b(a.z); r[3] = f2b(a.w);
  r[4] = f2b(b.x); r[5] = f2b(b.y); r[6] = f2b(b.z); r[7] = f2b(b.w);
  return r;
}

typedef const __attribute__((address_space(1))) unsigned int* gas1_t;
typedef __attribute__((address_space(3))) unsigned int* las3_t;
DI void gld16(const void* g, void* l) {
  __builtin_amdgcn_global_load_lds((gas1_t)g, (las3_t)l, 16, 0, 0);
}

// ---------------------------------------------------------------------------
// K1: qkv gemm, bf16 MFMA, f32 inputs reg-staged (inline f32->bf16 cvt).
// Out[g][c][n] (bf16) = sum_k Wg[c][k] * In[n][k].
// Tile 128c x 128n, K-step 32, double-buffered fragment-ordered LDS.
// ---------------------------------------------------------------------------
__global__ __launch_bounds__(256) void k_qkv(
    const float* __restrict__ x, const float* __restrict__ seg,
    const float* __restrict__ kv_w, const float* __restrict__ q_w,
    u16* __restrict__ qkv)
{
  __shared__ __align__(16) u16 As[2][4096];
  __shared__ __align__(16) u16 Bs[2][4096];
  const int t = threadIdx.x;
  const int lane = t & 63, wave = t >> 6;
  const int n0 = blockIdx.x * 128;
  const int c0 = blockIdx.y * 128;
  const int g  = blockIdx.z;
  const int grp = g >> 3, b = g & 7;
  const float* __restrict__ In = (grp == 0 ? seg : x) + (size_t)b * Nn * Cc;
  const float* __restrict__ Wg = (grp == 0) ? q_w : (kv_w + (grp == 2 ? Cc * Cc : 0));

  const int rA = lane & 15;
  const int kA = (lane >> 4) * 8;
  const int s0 = wave * 2, s1 = wave * 2 + 1;

#define STG(buf, k0)                                                          \
  {                                                                           \
    const float* ap0 = Wg + (size_t)(c0 + s0 * 16 + rA) * Cc + (k0) + kA;     \
    const float* ap1 = Wg + (size_t)(c0 + s1 * 16 + rA) * Cc + (k0) + kA;     \
    const float* bp0 = In + (size_t)(n0 + s0 * 16 + rA) * Cc + (k0) + kA;     \
    const float* bp1 = In + (size_t)(n0 + s1 * 16 + rA) * Cc + (k0) + kA;     \
    float4 a0 = *(const float4*)ap0, a1 = *(const float4*)(ap0 + 4);          \
    float4 a2 = *(const float4*)ap1, a3 = *(const float4*)(ap1 + 4);          \
    float4 b0 = *(const float4*)bp0, b1 = *(const float4*)(bp0 + 4);          \
    float4 b2 = *(const float4*)bp1, b3 = *(const float4*)(bp1 + 4);          \
    *(u16x8*)&As[buf][s0 * 512 + lane * 8] = pack8(a0, a1);                   \
    *(u16x8*)&As[buf][s1 * 512 + lane * 8] = pack8(a2, a3);                   \
    *(u16x8*)&Bs[buf][s0 * 512 + lane * 8] = pack8(b0, b1);                   \
    *(u16x8*)&Bs[buf][s1 * 512 + lane * 8] = pack8(b2, b3);                   \
  }

  f32x4 acc[4][4];
#pragma unroll
  for (int m = 0; m < 4; ++m)
#pragma unroll
    for (int n = 0; n < 4; ++n) acc[m][n] = (f32x4){0.f, 0.f, 0.f, 0.f};

  const int asub = (wave >> 1) * 4;
  const int bsub = (wave & 1) * 4;

  STG(0, 0);
  for (int ks = 0; ks < 8; ++ks) {
    __syncthreads();
    if (ks < 7) STG((ks + 1) & 1, (ks + 1) * 32);
    const int cur = ks & 1;
    bf16x8 af[4], bfr[4];
#pragma unroll
    for (int m = 0; m < 4; ++m)
      af[m] = *(const bf16x8*)&As[cur][(asub + m) * 512 + lane * 8];
#pragma unroll
    for (int n = 0; n < 4; ++n)
      bfr[n] = *(const bf16x8*)&Bs[cur][(bsub + n) * 512 + lane * 8];
#pragma unroll
    for (int m = 0; m < 4; ++m)
#pragma unroll
      for (int n = 0; n < 4; ++n)
        acc[m][n] = __builtin_amdgcn_mfma_f32_16x16x32_bf16(af[m], bfr[n], acc[m][n], 0, 0, 0);
  }
#undef STG

  const int wc = (wave >> 1) * 64, wn = (wave & 1) * 64;
  const int row4 = (lane >> 4) * 4, col = lane & 15;
  u16* __restrict__ op = qkv + (size_t)(g * Cc + c0 + wc) * Nn + n0 + wn;
#pragma unroll
  for (int m = 0; m < 4; ++m)
#pragma unroll
    for (int nn = 0; nn < 4; ++nn)
#pragma unroll
      for (int r = 0; r < 4; ++r)
        op[(size_t)(m * 16 + row4 + r) * Nn + nn * 16 + col] = f2b(acc[m][nn][r]);
}

// ---------------------------------------------------------------------------
// Depthwise conv on one 64x64 plane, f32 LDS (stride 72, col offset 4),
// bf16 in/out. Register-rolled rows.
// ---------------------------------------------------------------------------
template <int KS>
DI void dw_plane(const float* __restrict__ sp, const float* __restrict__ wl,
                 u16* __restrict__ dst, float bias, int t)
{
  constexpr int P = KS / 2;
  float wr[KS * KS];
#pragma unroll
  for (int i = 0; i < KS * KS; ++i) wr[i] = wl[i];
  const int x = t & 63;
  const int yb = (t >> 6) << 4;
  float acc[16];
#pragma unroll
  for (int i = 0; i < 16; ++i) acc[i] = bias;
#pragma unroll
  for (int r = 0; r < 16 + 2 * P; ++r) {
    float v[KS];
    const float* rp = sp + (yb + r + (3 - P)) * 72 + x + (4 - P);
#pragma unroll
    for (int dx = 0; dx < KS; ++dx) v[dx] = rp[dx];
#pragma unroll
    for (int dy = 0; dy < KS; ++dy) {
      const int yl = r - dy;
      if (yl >= 0 && yl < 16) {
        float s = acc[yl];
#pragma unroll
        for (int dx = 0; dx < KS; ++dx) s += wr[dy * KS + dx] * v[dx];
        acc[yl] = s;
      }
    }
  }
#pragma unroll
  for (int yl = 0; yl < 16; ++yl) dst[(yb + yl) * 64 + x] = f2b(acc[yl]);
}

DI void dw_stage(const u16* __restrict__ src, float* __restrict__ sp, int t)
{
  // zero apron: rows {0,1,2,67,68,69} full + cols {0..3,68..71} of rows 3..66
  for (int i = t; i < 944; i += 256) {
    if (i < 432) {
      int r6 = i / 72, cl = i - r6 * 72;
      int row = (r6 < 3) ? r6 : 64 + r6;
      sp[row * 72 + cl] = 0.f;
    } else {
      int i2 = i - 432;
      int row = 3 + (i2 >> 3), k = i2 & 7;
      int cl = (k < 4) ? k : 64 + k;
      sp[row * 72 + cl] = 0.f;
    }
  }
#pragma unroll
  for (int i = 0; i < 2; ++i) {
    int u = t + i * 256;
    int row = u >> 3, c8 = (u & 7) * 8;
    u16x8 v = *(const u16x8*)(src + row * 64 + c8);
    float4 f0 = make_float4(b2f(v[0]), b2f(v[1]), b2f(v[2]), b2f(v[3]));
    float4 f1 = make_float4(b2f(v[4]), b2f(v[5]), b2f(v[6]), b2f(v[7]));
    *(float4*)&sp[(row + 3) * 72 + 4 + c8] = f0;
    *(float4*)&sp[(row + 3) * 72 + 8 + c8] = f1;
  }
}

// K2: all depthwise convs feeding the pw stages (bf16 in/out).
__global__ __launch_bounds__(256) void k_dw(
    const u16* __restrict__ qkv,
    const float* __restrict__ a1w, const float* __restrict__ a2w,
    const float* __restrict__ a3w, const float* __restrict__ a0w,
    u16* __restrict__ dwout, u16* __restrict__ dwout0)
{
  __shared__ float sp[70 * 72];
  __shared__ float wl[49];
  const int t = threadIdx.x;
  const int p = blockIdx.x;
  const u16* src; u16* dst; const float* wsp; int ks;
  if (p < 4608) {
    int g = p / 192, c = p % 192, r = c >> 6;
    ks = 3 + 2 * r;
    wsp = (r == 0 ? a1w : (r == 1 ? a2w : a3w)) + (c & 63) * ks * ks;
    src = qkv + (size_t)(g * 256 + c) * Nn;
    dst = dwout + (size_t)p * Nn;
  } else {
    int q = p - 4608;
    int b = q / 192, j = q % 192;
    ks = 3;
    wsp = a0w + j * 9;
    src = qkv + (size_t)(((j >> 6) * 8 + b) * 256 + 192 + (j & 63)) * Nn;
    dst = dwout0 + (size_t)q * Nn;
  }
  if (t < 49) wl[t] = (t < ks * ks) ? wsp[t] : 0.f;
  dw_stage(src, sp, t);
  __syncthreads();
  if (ks == 3)      dw_plane<3>(sp, wl, dst, 0.f, t);
  else if (ks == 5) dw_plane<5>(sp, wl, dst, 0.f, t);
  else              dw_plane<7>(sp, wl, dst, 0.f, t);
}

// K7: crpe depthwise convs on the V images (bf16 in/out, bias).
__global__ __launch_bounds__(256) void k_crpe(
    const u16* __restrict__ xc,
    const float* __restrict__ w3, const float* __restrict__ b3,
    const float* __restrict__ w5, const float* __restrict__ b5,
    const float* __restrict__ w7, const float* __restrict__ b7,
    u16* __restrict__ conv_v)
{
  __shared__ float sp[70 * 72];
  __shared__ float wl[49];
  const int t = threadIdx.x;
  const int p = blockIdx.x;               // b*192 + ch
  const int b = p / 192, ch = p % 192;
  const float* wsp; float bias; int ks;
  if (ch < 48)       { ks = 3; wsp = w3 + ch * 9;          bias = b3[ch]; }
  else if (ch < 120) { ks = 5; wsp = w5 + (ch - 48) * 25;  bias = b5[ch - 48]; }
  else               { ks = 7; wsp = w7 + (ch - 120) * 49; bias = b7[ch - 120]; }
  const u16* src = xc + (size_t)((16 + b) * 192 + ch) * Nn;
  u16* dst = conv_v + (size_t)p * Nn;
  if (t < 49) wl[t] = (t < ks * ks) ? wsp[t] : 0.f;
  dw_stage(src, sp, t);
  __syncthreads();
  if (ks == 3)      dw_plane<3>(sp, wl, dst, bias, t);
  else if (ks == 5) dw_plane<5>(sp, wl, dst, bias, t);
  else              dw_plane<7>(sp, wl, dst, bias, t);
}

// ---------------------------------------------------------------------------
// K3: pointwise 64->64 + BN + hardswish via bf16 MFMA -> xc[g][r*64+co][n]
// Tile: co=64 x n=128, K=64 (2 MFMA K-steps). Dl [ci][n] stride 134;
// B-frag by 8x ds_read_u16; Wt [co][ci] stride 72, b128 A-frags.
// ---------------------------------------------------------------------------
__global__ __launch_bounds__(256) void k_pw_bn(
    const u16* __restrict__ dwout,
    const float* __restrict__ w1, const float* __restrict__ w2, const float* __restrict__ w3,
    const float* __restrict__ g1, const float* __restrict__ be1, const float* __restrict__ m1, const float* __restrict__ v1,
    const float* __restrict__ g2, const float* __restrict__ be2, const float* __restrict__ m2, const float* __restrict__ v2,
    const float* __restrict__ g3, const float* __restrict__ be3, const float* __restrict__ m3, const float* __restrict__ v3,
    u16* __restrict__ xc)
{
  constexpr int S2 = 134;
  __shared__ u16 Dl[64 * S2];
  __shared__ __align__(16) u16 Wt[64 * 72];
  __shared__ float scA[64], shA[64];
  const int t = threadIdx.x;
  const int lane = t & 63, wave = t >> 6;
  const int n0 = blockIdx.x * 128;
  const int r = blockIdx.y;
  const int g = blockIdx.z;
  const float* Wp = (r == 0 ? w1 : (r == 1 ? w2 : w3));
  const float* bg = (r == 0 ? g1 : (r == 1 ? g2 : g3));
  const float* bb = (r == 0 ? be1 : (r == 1 ? be2 : be3));
  const float* bm = (r == 0 ? m1 : (r == 1 ? m2 : m3));
  const float* bv = (r == 0 ? v1 : (r == 1 ? v2 : v3));

  {   // weights -> Wt
    int co = t >> 2, ci0 = (t & 3) * 16;
    const float* wp = Wp + co * 64 + ci0;
    float4 w0 = *(const float4*)wp,       wq = *(const float4*)(wp + 4);
    float4 w2_ = *(const float4*)(wp + 8), w3_ = *(const float4*)(wp + 12);
    *(u16x8*)&Wt[co * 72 + ci0] = pack8(w0, wq);
    *(u16x8*)&Wt[co * 72 + ci0 + 8] = pack8(w2_, w3_);
  }
  if (t < 64) {
    float sc = bg[t] * rsqrtf(bv[t] + 1e-5f);
    scA[t] = sc; shA[t] = bb[t] - bm[t] * sc;
  }
  const u16* dbase = dwout + (size_t)(g * 192 + r * 64) * Nn + n0;
#pragma unroll
  for (int i2 = 0; i2 < 4; ++i2) {
    int u = t + i2 * 256;
    int ci = u >> 4, nu = u & 15;
    u16x8 v = *(const u16x8*)(dbase + (size_t)ci * Nn + nu * 8);
    union { u16x8 v; unsigned int w[4]; } cc; cc.v = v;
    int base = ci * S2 + nu * 8;
#pragma unroll
    for (int w = 0; w < 4; ++w) *(unsigned int*)&Dl[base + 2 * w] = cc.w[w];
  }
  __syncthreads();

  f32x4 acc[4][2];
#pragma unroll
  for (int m = 0; m < 4; ++m)
#pragma unroll
    for (int n = 0; n < 2; ++n) acc[m][n] = (f32x4){0.f, 0.f, 0.f, 0.f};

#pragma unroll
  for (int ks = 0; ks < 2; ++ks) {
    const int kbase = ks * 32 + (lane >> 4) * 8;
    bf16x8 af[4];
#pragma unroll
    for (int m = 0; m < 4; ++m)
      af[m] = *(const bf16x8*)&Wt[(m * 16 + (lane & 15)) * 72 + kbase];
#pragma unroll
    for (int nl = 0; nl < 2; ++nl) {
      const int ncol = (wave * 2 + nl) * 16 + (lane & 15);
      bf16x8 bf;
#pragma unroll
      for (int j = 0; j < 8; ++j) bf[j] = (short)Dl[(kbase + j) * S2 + ncol];
#pragma unroll
      for (int m = 0; m < 4; ++m)
        acc[m][nl] = __builtin_amdgcn_mfma_f32_16x16x32_bf16(af[m], bf, acc[m][nl], 0, 0, 0);
    }
  }

  const int row4 = (lane >> 4) * 4, col = lane & 15;
#pragma unroll
  for (int m = 0; m < 4; ++m)
#pragma unroll
    for (int nl = 0; nl < 2; ++nl) {
      int nn = (wave * 2 + nl) * 16 + col;
      u16* op = xc + (size_t)(g * 192 + r * 64 + m * 16 + row4) * Nn + n0 + nn;
#pragma unroll
      for (int rr = 0; rr < 4; ++rr) {
        int co = m * 16 + row4 + rr;
        float v = acc[m][nl][rr] * scA[co] + shA[co];
        op[(size_t)rr * Nn] = f2b(hswish(v));
      }
    }
}

// ---------------------------------------------------------------------------
// K4: agg0 pointwise 192->64 + in-register layernorm + hardswish
// -> x_agg0[b][n][co] bf16. MFMA, K chunked by 64.
// ---------------------------------------------------------------------------
__global__ __launch_bounds__(256) void k_pw_ln(
    const u16* __restrict__ dwout0, const float* __restrict__ pw,
    const float* __restrict__ lng, const float* __restrict__ lnb,
    u16* __restrict__ x_agg0)
{
  constexpr int S2 = 134;
  __shared__ u16 Dl[64 * S2];
  __shared__ __align__(16) u16 Wt[64 * 200];
  __shared__ float lgA[64], lbA[64];
  const int t = threadIdx.x;
  const int lane = t & 63, wave = t >> 6;
  const int n0 = blockIdx.x * 128;
  const int b = blockIdx.y;

#pragma unroll
  for (int i = 0; i < 12; ++i) {
    int u = t + i * 256;                  // < 3072 float4 units
    int co = u / 48, rem = u - co * 48;
    float4 w = *(const float4*)(pw + co * 192 + rem * 4);
    ushort4 o; o.x = f2b(w.x); o.y = f2b(w.y); o.z = f2b(w.z); o.w = f2b(w.w);
    *(ushort4*)&Wt[co * 200 + rem * 4] = o;
  }
  if (t < 64) { lgA[t] = lng[t]; lbA[t] = lnb[t]; }

  f32x4 acc[4][2];
#pragma unroll
  for (int m = 0; m < 4; ++m)
#pragma unroll
    for (int n = 0; n < 2; ++n) acc[m][n] = (f32x4){0.f, 0.f, 0.f, 0.f};

  for (int kc = 0; kc < 192; kc += 64) {
    if (kc) __syncthreads();
    const u16* dbase = dwout0 + (size_t)(b * 192 + kc) * Nn + n0;
#pragma unroll
    for (int i2 = 0; i2 < 4; ++i2) {
      int u = t + i2 * 256;
      int ci = u >> 4, nu = u & 15;
      u16x8 v = *(const u16x8*)(dbase + (size_t)ci * Nn + nu * 8);
      union { u16x8 v; unsigned int w[4]; } cc; cc.v = v;
      int base = ci * S2 + nu * 8;
#pragma unroll
      for (int w = 0; w < 4; ++w) *(unsigned int*)&Dl[base + 2 * w] = cc.w[w];
    }
    __syncthreads();
#pragma unroll
    for (int ks = 0; ks < 2; ++ks) {
      const int kbase = ks * 32 + (lane >> 4) * 8;
      bf16x8 af[4];
#pragma unroll
      for (int m = 0; m < 4; ++m)
        af[m] = *(const bf16x8*)&Wt[(m * 16 + (lane & 15)) * 200 + kc + kbase];
#pragma unroll
      for (int nl = 0; nl < 2; ++nl) {
        const int ncol = (wave * 2 + nl) * 16 + (lane & 15);
        bf16x8 bf;
#pragma unroll
        for (int j = 0; j < 8; ++j) bf[j] = (short)Dl[(kbase + j) * S2 + ncol];
#pragma unroll
        for (int m = 0; m < 4; ++m)
          acc[m][nl] = __builtin_amdgcn_mfma_f32_16x16x32_bf16(af[m], bf, acc[m][nl], 0, 0, 0);
      }
    }
  }

  // in-register LN over co=64 (rows): per-lane 16-row partials + shfl over
  // lane bits 4,5 (row-group exchange; col = lane&15 invariant).
  const int row4 = (lane >> 4) * 4, col = lane & 15;
#pragma unroll
  for (int nl = 0; nl < 2; ++nl) {
    float s = 0.f, q = 0.f;
#pragma unroll
    for (int m = 0; m < 4; ++m)
#pragma unroll
      for (int rr = 0; rr < 4; ++rr) {
        float v = acc[m][nl][rr];
        s += v; q += v * v;
      }
    s += __shfl_xor(s, 16, 64); q += __shfl_xor(q, 16, 64);
    s += __shfl_xor(s, 32, 64); q += __shfl_xor(q, 32, 64);
    float mu = s * (1.f / 64.f);
    float var = q * (1.f / 64.f) - mu * mu;
    float is = rsqrtf(var + 1e-5f);
    int nn = (wave * 2 + nl) * 16 + col;
    u16* op = x_agg0 + (size_t)((b << 12) + n0 + nn) * 64;
#pragma unroll
    for (int m = 0; m < 4; ++m) {
      ushort4 o;
#pragma unroll
      for (int rr = 0; rr < 4; ++rr) {
        int co = m * 16 + row4 + rr;
        float v = (acc[m][nl][rr] - mu) * is * lgA[co] + lbA[co];
        ((u16*)&o)[rr] = f2b(hswish(v));
      }
      *(ushort4*)&op[m * 16 + row4] = o;
    }
  }
}

// ---------------------------------------------------------------------------
// K5: per-(b,h,c) softmax stats over N: ls = max + log(sum(exp(x-max)))
// ---------------------------------------------------------------------------
__global__ __launch_bounds__(256) void k_sm(const u16* __restrict__ xc,
                                            float* __restrict__ ls)
{
  __shared__ float rA[4], rB[4];
  const int rho = blockIdx.x;             // b*192 + h*24 + c
  const int b = rho / 192, rem = rho % 192;
  const u16* row = xc + (size_t)((8 + b) * 192 + rem) * Nn;
  const int t = threadIdx.x;
  float v[16];
#pragma unroll
  for (int i = 0; i < 16; ++i) v[i] = b2f(row[t + i * 256]);
  float m = v[0];
#pragma unroll
  for (int i = 1; i < 16; ++i) m = fmaxf(m, v[i]);
#pragma unroll
  for (int off = 32; off > 0; off >>= 1) m = fmaxf(m, __shfl_xor(m, off, 64));
  if ((t & 63) == 0) rA[t >> 6] = m;
  __syncthreads();
  m = fmaxf(fmaxf(rA[0], rA[1]), fmaxf(rA[2], rA[3]));
  float s = 0.f;
#pragma unroll
  for (int i = 0; i < 16; ++i) s += __expf(v[i] - m);
#pragma unroll
  for (int off = 32; off > 0; off >>= 1) s += __shfl_xor(s, off, 64);
  if ((t & 63) == 0) rB[t >> 6] = s;
  __syncthreads();
  if (t == 0) ls[rho] = m + __logf(rB[0] + rB[1] + rB[2] + rB[3]);
}

// ---------------------------------------------------------------------------
// K6: ktv[b,h,k,v] = sum_n exp(kh-ls) * vh, 8 N-chunks, atomicAdd.
// ---------------------------------------------------------------------------
__global__ __launch_bounds__(576) void k_ktv(const u16* __restrict__ xc,
                                             const float* __restrict__ ls,
                                             float* __restrict__ ktv)
{
  __shared__ float pb[24][65];
  __shared__ float vb[24][65];
  __shared__ float lsl[24];
  const int nc = blockIdx.x, h = blockIdx.y, b = blockIdx.z;
  const int t = threadIdx.x;
  if (t < 24) lsl[t] = ls[(b * 8 + h) * 24 + t];
  __syncthreads();
  const int kk = t / 24, vv = t % 24;
  const u16* kbase = xc + (size_t)((8 + b) * 192 + h * 24) * Nn;
  const u16* vbase = xc + (size_t)((16 + b) * 192 + h * 24) * Nn;
  const int nb0 = nc * 512;
  float accv = 0.f;
  for (int sub = 0; sub < 8; ++sub) {
    int nbase = nb0 + sub * 64;
    for (int e = t; e < 1536; e += 576) {
      int ch = e >> 6, n = e & 63;
      pb[ch][n] = __expf(b2f(kbase[(size_t)ch * Nn + nbase + n]) - lsl[ch]);
      vb[ch][n] = b2f(vbase[(size_t)ch * Nn + nbase + n]);
    }
    __syncthreads();
    float a = 0.f;
#pragma unroll 16
    for (int i = 0; i < 64; ++i) a += pb[kk][i] * vb[vv][i];
    accv += a;
    __syncthreads();
  }
  atomicAdd(&ktv[((b * 8 + h) * 24 + kk) * 24 + vv], accv);
}

// ---------------------------------------------------------------------------
// K8: assemble catb (bf16): [b][n][0:192] = scale*(q@ktv)+q*conv_v,
// [192:256] = x_agg0 (bf16 copy).
// ---------------------------------------------------------------------------
__global__ __launch_bounds__(256) void k_cat(
    const u16* __restrict__ xc, const u16* __restrict__ conv_v,
    const float* __restrict__ ktv, const u16* __restrict__ x_agg0,
    u16* __restrict__ catb)
{
  __shared__ float kt[4608];
  const int t = threadIdx.x;
  const int b = blockIdx.y;
  for (int e = t; e < 4608; e += 256) kt[e] = ktv[b * 4608 + e];
  __syncthreads();
  const int nl = t & 63;
  const int grp = t >> 6;
  const int n = blockIdx.x * 64 + nl;
  const float scale = 0.17677669529663687f;   // 32^-0.5
#pragma unroll
  for (int hh = 0; hh < 2; ++hh) {
    const int h = grp * 2 + hh;
    const u16* qb = xc + (size_t)(b * 192 + h * 24) * Nn + n;
    float q[24];
#pragma unroll
    for (int c = 0; c < 24; ++c) q[c] = b2f(qb[(size_t)c * Nn]);
    float ev[24];
#pragma unroll
    for (int v = 0; v < 24; ++v) ev[v] = 0.f;
    const float* kth = kt + h * 576;
#pragma unroll
    for (int k = 0; k < 24; ++k) {
      const float qk = q[k];
#pragma unroll
      for (int v = 0; v < 24; ++v) ev[v] += qk * kth[k * 24 + v];
    }
    const u16* cvb = conv_v + (size_t)(b * 192 + h * 24) * Nn + n;
    u16* ob = catb + ((size_t)(b * 4096 + n)) * 256 + h * 24;
#pragma unroll
    for (int v4 = 0; v4 < 6; ++v4) {
      ushort4 o;
      o.x = f2b(scale * ev[v4 * 4 + 0] + q[v4 * 4 + 0] * b2f(cvb[(size_t)(v4 * 4 + 0) * Nn]));
      o.y = f2b(scale * ev[v4 * 4 + 1] + q[v4 * 4 + 1] * b2f(cvb[(size_t)(v4 * 4 + 1) * Nn]));
      o.z = f2b(scale * ev[v4 * 4 + 2] + q[v4 * 4 + 2] * b2f(cvb[(size_t)(v4 * 4 + 2) * Nn]));
      o.w = f2b(scale * ev[v4 * 4 + 3] + q[v4 * 4 + 3] * b2f(cvb[(size_t)(v4 * 4 + 3) * Nn]));
      *(ushort4*)(ob + v4 * 4) = o;
    }
  }
  const u16* xa = x_agg0 + ((size_t)(b * 4096 + blockIdx.x * 64)) * 64;
  u16* cb = catb + ((size_t)(b * 4096 + blockIdx.x * 64)) * 256 + 192;
  for (int e2 = t; e2 < 4096; e2 += 256) {
    int nn = e2 >> 6, cc = e2 & 63;
    cb[(size_t)nn * 256 + cc] = xa[(size_t)nn * 64 + cc];
  }
}

// ---------------------------------------------------------------------------
// K9: out[m][c] = sum_k catb[m][k]*proj_w[c][k] + pb[c]. A via gld16 (bf16),
// B reg-staged from f32 proj_w. f32 out.
// ---------------------------------------------------------------------------
__global__ __launch_bounds__(256) void k_proj(
    const u16* __restrict__ catb, const float* __restrict__ pwf,
    const float* __restrict__ pb, float* __restrict__ out)
{
  __shared__ __align__(16) u16 As[2][4096];
  __shared__ __align__(16) u16 Bs[2][4096];
  const int t = threadIdx.x;
  const int lane = t & 63, wave = t >> 6;
  const int m0 = blockIdx.x * 128;
  const int c0 = blockIdx.y * 128;
  const int rA = lane & 15;
  const int kA = (lane >> 4) * 8;
  const int s0 = wave * 2, s1 = wave * 2 + 1;

#define STG(buf, k0)                                                          \
  {                                                                           \
    gld16(catb + (size_t)(m0 + s0 * 16 + rA) * 256 + (k0) + kA, &As[buf][s0 * 512]); \
    gld16(catb + (size_t)(m0 + s1 * 16 + rA) * 256 + (k0) + kA, &As[buf][s1 * 512]); \
    const float* bp0 = pwf + (size_t)(c0 + s0 * 16 + rA) * 256 + (k0) + kA;   \
    const float* bp1 = pwf + (size_t)(c0 + s1 * 16 + rA) * 256 + (k0) + kA;   \
    float4 b0 = *(const float4*)bp0, b1 = *(const float4*)(bp0 + 4);          \
    float4 b2 = *(const float4*)bp1, b3 = *(const float4*)(bp1 + 4);          \
    *(u16x8*)&Bs[buf][s0 * 512 + lane * 8] = pack8(b0, b1);                   \
    *(u16x8*)&Bs[buf][s1 * 512 + lane * 8] = pack8(b2, b3);                   \
  }

  f32x4 acc[4][4];
#pragma unroll
  for (int m = 0; m < 4; ++m)
#pragma unroll
    for (int n = 0; n < 4; ++n) acc[m][n] = (f32x4){0.f, 0.f, 0.f, 0.f};

  const int asub = (wave >> 1) * 4;
  const int bsub = (wave & 1) * 4;

  STG(0, 0);
  for (int ks = 0; ks < 8; ++ks) {
    __syncthreads();
    if (ks < 7) STG((ks + 1) & 1, (ks + 1) * 32);
    const int cur = ks & 1;
    bf16x8 af[4], bfr[4];
#pragma unroll
    for (int m = 0; m < 4; ++m)
      af[m] = *(const bf16x8*)&As[cur][(asub + m) * 512 + lane * 8];
#pragma unroll
    for (int n = 0; n < 4; ++n)
      bfr[n] = *(const bf16x8*)&Bs[cur][(bsub + n) * 512 + lane * 8];
#pragma unroll
    for (int m = 0; m < 4; ++m)
#pragma unroll
      for (int n = 0; n < 4; ++n)
        acc[m][n] = __builtin_amdgcn_mfma_f32_16x16x32_bf16(af[m], bfr[n], acc[m][n], 0, 0, 0);
  }
#undef STG

  const int wm = (wave >> 1) * 64, wn = (wave & 1) * 64;
  const int row4 = (lane >> 4) * 4, col = lane & 15;
  float pbv[4];
#pragma unroll
  for (int nn = 0; nn < 4; ++nn) pbv[nn] = pb[c0 + wn + nn * 16 + col];
  float* __restrict__ op = out + (size_t)(m0 + wm) * 256 + c0 + wn;
#pragma unroll
  for (int mi = 0; mi < 4; ++mi)
#pragma unroll
    for (int nn = 0; nn < 4; ++nn)
#pragma unroll
      for (int r = 0; r < 4; ++r)
        op[(size_t)(mi * 16 + row4 + r) * 256 + nn * 16 + col] = acc[mi][nn][r] + pbv[nn];
}

// ---------------------------------------------------------------------------
extern "C" void kernel_launch(void* const* d_in, const int* in_sizes, int n_in,
                              void* d_out, int out_size, void* d_ws, size_t ws_size,
                              hipStream_t stream)
{
  const float* x       = (const float*)d_in[0];
  const float* seg     = (const float*)d_in[1];
  const float* kv_w    = (const float*)d_in[2];
  const float* q_w     = (const float*)d_in[3];
  const float* proj_w  = (const float*)d_in[4];
  const float* proj_b  = (const float*)d_in[5];
  const float* agg0_dw = (const float*)d_in[6];
  const float* agg0_pw = (const float*)d_in[7];
  const float* ln_g    = (const float*)d_in[8];
  const float* ln_b    = (const float*)d_in[9];
  const float* agg1_dw = (const float*)d_in[10];
  const float* agg1_pw = (const float*)d_in[11];
  const float* bn1_g   = (const float*)d_in[12];
  const float* bn1_b   = (const float*)d_in[13];
  const float* bn1_m   = (const float*)d_in[14];
  const float* bn1_v   = (const float*)d_in[15];
  const float* agg2_dw = (const float*)d_in[16];
  const float* agg2_pw = (const float*)d_in[17];
  const float* bn2_g   = (const float*)d_in[18];
  const float* bn2_b   = (const float*)d_in[19];
  const float* bn2_m   = (const float*)d_in[20];
  const float* bn2_v   = (const float*)d_in[21];
  const float* agg3_dw = (const float*)d_in[22];
  const float* agg3_pw = (const float*)d_in[23];
  const float* bn3_g   = (const float*)d_in[24];
  const float* bn3_b   = (const float*)d_in[25];
  const float* bn3_m   = (const float*)d_in[26];
  const float* bn3_v   = (const float*)d_in[27];
  const float* crpe_w3 = (const float*)d_in[28];
  const float* crpe_b3 = (const float*)d_in[29];
  const float* crpe_w5 = (const float*)d_in[30];
  const float* crpe_b5 = (const float*)d_in[31];
  const float* crpe_w7 = (const float*)d_in[32];
  const float* crpe_b7 = (const float*)d_in[33];

  float* ws = (float*)d_ws;
  u16*   qkv_b  = (u16*)(ws);                 // 25165824 u16
  u16*   dwout  = (u16*)(ws + 12582912);      // 18874368 u16
  u16*   dwout0 = (u16*)(ws + 22020096);      //  6291456 u16
  u16*   xc_b   = (u16*)(ws + 25165824);      // 25165824 u16
  u16*   conv_v = (u16*)(ws + 37748736);      //  6291456 u16
  u16*   x_agg0 = (u16*)(ws + 40894464);      //  2097152 u16
  float* ls     = ws + 41943040;              // 1536 f
  float* ktv    = ws + 41944576;              // 36864 f
  u16*   catb   = (u16*)(ws + 41981440);      //  8388608 u16
  float* out    = (float*)d_out;

  hipMemsetAsync(ktv, 0, 36864 * sizeof(float), stream);

  k_qkv<<<dim3(32, 2, 24), 256, 0, stream>>>(x, seg, kv_w, q_w, qkv_b);
  k_dw<<<dim3(6144), 256, 0, stream>>>(qkv_b, agg1_dw, agg2_dw, agg3_dw, agg0_dw,
                                       dwout, dwout0);
  k_pw_bn<<<dim3(32, 3, 24), 256, 0, stream>>>(
      dwout, agg1_pw, agg2_pw, agg3_pw,
      bn1_g, bn1_b, bn1_m, bn1_v,
      bn2_g, bn2_b, bn2_m, bn2_v,
      bn3_g, bn3_b, bn3_m, bn3_v, xc_b);
  k_pw_ln<<<dim3(32, 8), 256, 0, stream>>>(dwout0, agg0_pw, ln_g, ln_b, x_agg0);
  k_sm<<<dim3(1536), 256, 0, stream>>>(xc_b, ls);
  k_ktv<<<dim3(8, 8, 8), 576, 0, stream>>>(xc_b, ls, ktv);
  k_crpe<<<dim3(1536), 256, 0, stream>>>(xc_b, crpe_w3, crpe_b3, crpe_w5,
                                         crpe_b5, crpe_w7, crpe_b7, conv_v);
  k_cat<<<dim3(64, 8), 256, 0, stream>>>(xc_b, conv_v, ktv, x_agg0, catb);
  k_proj<<<dim3(256, 2), 256, 0, stream>>>(catb, proj_w, proj_b, out);
}